// Round 6
// baseline (495.187 us; speedup 1.0000x reference)
//
#include <hip/hip_runtime.h>
#include <math.h>

#define N_USERS    50000
#define N_ENTITIES 100000
#define N_NODES    150000
#define N_EDGES    3000000
#define BATCH      8192
#define SLOPE      0.2f
#define EPSF       1e-12f

// bucket partition: bucket = h>>6 (64 nodes per bucket)
#define NBUK   2344            // ceil(150000/64)
#define CAP    1536            // per-bucket real-record capacity (mean 1280, +7.1 sd)
#define STR    2560            // physical bucket stride: CAP + 64*16 padding worst case
#define PADM   16              // per-node segment padded to multiple of 16 edges
#define BLK_E  12288           // edges per partition block (12 per thread)
#define NPB    ((N_EDGES + BLK_E - 1) / BLK_E)   // 245
#define PBLK   1024            // partition block size (16 waves)
#define EPT    (BLK_E / PBLK)  // 12 edges per thread
#define CH     4096            // copy-out chunk (positions per LDS flush)
#define GC_STRIDE 16           // gcursor padded: 1 counter per 64B line
#define CASTB  ((N_NODES * 64 / 4 + PBLK - 1) / PBLK)   // 2344 cast blocks

__device__ __forceinline__ unsigned f2bf(float f) {       // RNE fp32->bf16
    unsigned u = __float_as_uint(f);
    return (u + 0x7FFFu + ((u >> 16) & 1u)) >> 16;
}
__device__ __forceinline__ float bf_lo(unsigned d) { return __uint_as_float(d << 16); }
// hi bf16 WITHOUT masking low bits: garbage adds <=2^-16 relative error,
// strictly dominated by the 2^-9 bf16 rounding already present.
__device__ __forceinline__ float bf_hi(unsigned d) { return __uint_as_float(d); }

// ---------------------------------------------------------------------------
// prep_k: merged partition (blocks < NPB) + bf16 cast (blocks >= NPB).
// The two are independent; merging lets cast0's streaming blocks co-schedule
// into partition's latency stalls instead of running serially after it.
// Partition body = R2-verified register-staged bucket scatter.
// ---------------------------------------------------------------------------
__global__ __launch_bounds__(PBLK)
void prep_k(const int* __restrict__ all_h, const int* __restrict__ all_t,
            const float* __restrict__ A,
            int* __restrict__ gcursor, int2* __restrict__ rec,
            const float* __restrict__ user_emb, const float* __restrict__ ent_emb,
            unsigned short* __restrict__ ego0_bf) {
    __shared__ int pos[NBUK];      // counts -> excl starts -> cursors
    __shared__ int gofs[NBUK];     // global_base - local_start per bucket
    __shared__ int wsum[PBLK / 64];
    __shared__ int2 srec[CH];      // staged records for current chunk
    __shared__ int  sdst[CH];      // staged global slots (-1 = dropped)

    int t = threadIdx.x;

    if (blockIdx.x >= NPB) {
        // ---- cast body: concat(user,ent) -> bf16 table ----
        int idx = (blockIdx.x - NPB) * PBLK + t;
        const int total = N_NODES * 64 / 4;
        if (idx >= total) return;
        int ge = idx * 4;
        const float* src = (ge < N_USERS * 64) ? user_emb + ge
                                               : ent_emb + (ge - N_USERS * 64);
        float4 v = *(const float4*)src;
        ushort4 o;
        o.x = (unsigned short)f2bf(v.x);
        o.y = (unsigned short)f2bf(v.y);
        o.z = (unsigned short)f2bf(v.z);
        o.w = (unsigned short)f2bf(v.w);
        *(ushort4*)(ego0_bf + ge) = o;
        return;
    }

    // ---- partition body ----
    for (int i = t; i < NBUK; i += PBLK) pos[i] = 0;
    __syncthreads();

    int e0 = blockIdx.x * BLK_E;
    int e1 = e0 + BLK_E; if (e1 > N_EDGES) e1 = N_EDGES;
    int tot = e1 - e0;

    // single coalesced read of all three edge streams into registers
    int h[EPT]; int tt[EPT]; float aa[EPT];
    #pragma unroll
    for (int k = 0; k < EPT; ++k) {
        int e = e0 + k * PBLK + t;
        bool v = e < e1;
        h[k]  = v ? all_h[e] : -1;
        tt[k] = v ? all_t[e] : 0;
        aa[k] = v ? A[e] : 0.f;
    }
    #pragma unroll
    for (int k = 0; k < EPT; ++k)
        if (h[k] >= 0) atomicAdd(&pos[h[k] >> 6], 1);
    __syncthreads();

    // sweep 1: read own counts, reserve global space (padded counter lines)
    int c[3], g[3];
    int i0 = t * 3;
    int tsum = 0;
    #pragma unroll
    for (int j = 0; j < 3; ++j) {
        int idx = i0 + j;
        c[j] = (idx < NBUK) ? pos[idx] : 0;
        tsum += c[j];
        g[j] = (idx < NBUK && c[j]) ? atomicAdd(&gcursor[idx * GC_STRIDE], c[j]) : 0;
    }

    // block-wide exclusive scan of per-thread sums (16 waves of 64)
    int lane = t & 63, w = t >> 6;
    int incl = tsum;
    #pragma unroll
    for (int off = 1; off < 64; off <<= 1) {
        int x = __shfl_up(incl, off, 64);
        if (lane >= off) incl += x;
    }
    if (lane == 63) wsum[w] = incl;
    __syncthreads();
    int wbase = 0;
    for (int j = 0; j < w; ++j) wbase += wsum[j];
    int excl = wbase + (incl - tsum);

    // sweep 2: exclusive starts into pos; gofs folds global base - local start
    #pragma unroll
    for (int j = 0; j < 3; ++j) {
        int idx = i0 + j;
        if (idx < NBUK) { pos[idx] = excl; gofs[idx] = g[j] - excl; }
        excl += c[j];
    }
    __syncthreads();

    // placement: block-sorted position p + final global slot per edge (regs)
    int pp[EPT], gd[EPT];
    #pragma unroll
    for (int k = 0; k < EPT; ++k) {
        if (h[k] >= 0) {
            int b = h[k] >> 6;
            int p = atomicAdd(&pos[b], 1);
            pp[k] = p;
            int gr = gofs[b] + p;              // global rank within bucket
            gd[k] = (gr < CAP) ? b * STR + gr : -1;
        } else {
            pp[k] = -1; gd[k] = -1;
        }
    }

    // chunked reg->LDS scatter + linear coalesced flush
    for (int base = 0; base < tot; base += CH) {
        __syncthreads();                       // LDS chunk free (prev flush done)
        int lim = tot - base; if (lim > CH) lim = CH;
        #pragma unroll
        for (int k = 0; k < EPT; ++k) {
            int s = pp[k] - base;
            if (s >= 0 && s < CH) {
                srec[s] = make_int2(tt[k] | ((h[k] & 63) << 18), __float_as_int(aa[k]));
                sdst[s] = gd[k];
            }
        }
        __syncthreads();
        for (int s = t; s < lim; s += PBLK) {
            int d = sdst[s];
            if (d >= 0) rec[d] = srec[s];
        }
    }
}

// ---------------------------------------------------------------------------
// local_sort_k: per-bucket 64-bin counting sort in LDS -> h-grouped records,
// each node's segment PADDED to a multiple of PADM(16) with zero records
// {t=0, a=0}. Padding guarantees every 8/16-slot block a wave touches is
// initialized -> side_k needs only block-granular (wave-uniform) predicates.
// ---------------------------------------------------------------------------
__global__ __launch_bounds__(256)
void local_sort_k(const int* __restrict__ gcursor, int2* __restrict__ rec,
                  int2* __restrict__ range) {
    __shared__ int2 sin[CAP];
    __shared__ int2 sout[STR];
    __shared__ int cnt64[64];
    __shared__ int pos64[64];
    __shared__ int s_ptot;
    int b = blockIdx.x, t = threadIdx.x;
    int cnt = gcursor[(size_t)b * GC_STRIDE]; if (cnt > CAP) cnt = CAP;

    if (t < 64) cnt64[t] = 0;
    __syncthreads();

    for (int i = t; i < cnt; i += 256) {
        int2 p = rec[(size_t)b * STR + i];
        sin[i] = p;
        atomicAdd(&cnt64[(p.x >> 18) & 63], 1);
    }
    __syncthreads();

    if (t < 64) {
        int v = cnt64[t];
        int pv = (v + PADM - 1) & ~(PADM - 1);
        int sum = pv;
        #pragma unroll
        for (int off = 1; off < 64; off <<= 1) {
            int x = __shfl_up(sum, off, 64);
            if (t >= off) sum += x;
        }
        pos64[t] = sum - pv;
        if (t == 63) s_ptot = sum;
    }
    __syncthreads();
    int ptot = s_ptot;

    // zero padded region, then scatter real records into padded positions
    for (int i = t; i < ptot; i += 256) sout[i] = make_int2(0, 0);
    __syncthreads();

    for (int i = t; i < cnt; i += 256) {
        int2 p = sin[i];
        int l = (p.x >> 18) & 63;
        int dst = atomicAdd(&pos64[l], 1);
        sout[dst] = make_int2(p.x & 0x3FFFF, p.y);
    }
    __syncthreads();

    for (int i = t; i < ptot; i += 256)
        rec[(size_t)b * STR + i] = sout[i];

    if (t < 64) {
        int v = cnt64[t];
        int pv = (v + PADM - 1) & ~(PADM - 1);
        int sum = pv;
        #pragma unroll
        for (int off = 1; off < 64; off <<= 1) {
            int x = __shfl_up(sum, off, 64);
            if (t >= off) sum += x;
        }
        int start = b * STR + (sum - pv);
        int node = b * 64 + t;
        if (node < N_NODES) range[node] = make_int2(start, start + pv);
    }
}

// ---------------------------------------------------------------------------
// side_k: wave-per-node segment-sum over bf16 rows (R4-verified: 63.3us,
// the measured rate limit for random 128B gathers; R5's 4-node batching
// proved MLP is not the bottleneck). Ranges padded to multiple of 16 ->
// no bounds clamping. rec loads NONTEMPORAL: read-once stream, keep the
// bf16 table hot in per-XCD L2 instead.
// ---------------------------------------------------------------------------
template<int DIN>
__global__ __launch_bounds__(256)
void side_k(const int2* __restrict__ range, const int2* __restrict__ rec,
            const unsigned short* __restrict__ tab, float* __restrict__ side) {
    constexpr int LPR = DIN / 8;       // 8 (D64), 4 (D32)
    constexpr int EPW = 64 / LPR;      // 8 (D64), 16 (D32)

    int w = threadIdx.x >> 6;
    int lane = threadIdx.x & 63;
    int h = blockIdx.x * 4 + w;

    int2 rg = range[h];
    int e0 = rg.x, e1 = rg.y;          // e1 - e0 is a multiple of 16
    int g = lane / LPR;
    int q = lane % LPR;

    const unsigned long long* recq = (const unsigned long long*)rec;

    float acc[8];
    #pragma unroll
    for (int j = 0; j < 8; ++j) acc[j] = 0.f;

    int e = e0;
    for (; e + 2 * EPW <= e1; e += 2 * EPW) {
        unsigned long long r0 = __builtin_nontemporal_load(recq + e + g);
        unsigned long long r1 = __builtin_nontemporal_load(recq + e + EPW + g);
        int   x0 = (int)(r0 & 0xFFFFFFFFull);
        float a0 = __uint_as_float((unsigned)(r0 >> 32));
        int   x1 = (int)(r1 & 0xFFFFFFFFull);
        float a1 = __uint_as_float((unsigned)(r1 >> 32));
        uint4 d0 = *(const uint4*)(tab + (unsigned)(x0 * DIN) + q * 8);
        uint4 d1 = *(const uint4*)(tab + (unsigned)(x1 * DIN) + q * 8);
        acc[0] = fmaf(a0, bf_lo(d0.x), acc[0]);
        acc[1] = fmaf(a0, bf_hi(d0.x), acc[1]);
        acc[2] = fmaf(a0, bf_lo(d0.y), acc[2]);
        acc[3] = fmaf(a0, bf_hi(d0.y), acc[3]);
        acc[4] = fmaf(a0, bf_lo(d0.z), acc[4]);
        acc[5] = fmaf(a0, bf_hi(d0.z), acc[5]);
        acc[6] = fmaf(a0, bf_lo(d0.w), acc[6]);
        acc[7] = fmaf(a0, bf_hi(d0.w), acc[7]);
        acc[0] = fmaf(a1, bf_lo(d1.x), acc[0]);
        acc[1] = fmaf(a1, bf_hi(d1.x), acc[1]);
        acc[2] = fmaf(a1, bf_lo(d1.y), acc[2]);
        acc[3] = fmaf(a1, bf_hi(d1.y), acc[3]);
        acc[4] = fmaf(a1, bf_lo(d1.z), acc[4]);
        acc[5] = fmaf(a1, bf_hi(d1.z), acc[5]);
        acc[6] = fmaf(a1, bf_lo(d1.w), acc[6]);
        acc[7] = fmaf(a1, bf_hi(d1.w), acc[7]);
    }
    if (e < e1) {                      // remainder is exactly EPW (D32 only)
        unsigned long long r0 = __builtin_nontemporal_load(recq + e + g);
        int   x0 = (int)(r0 & 0xFFFFFFFFull);
        float a0 = __uint_as_float((unsigned)(r0 >> 32));
        uint4 d0 = *(const uint4*)(tab + (unsigned)(x0 * DIN) + q * 8);
        acc[0] = fmaf(a0, bf_lo(d0.x), acc[0]);
        acc[1] = fmaf(a0, bf_hi(d0.x), acc[1]);
        acc[2] = fmaf(a0, bf_lo(d0.y), acc[2]);
        acc[3] = fmaf(a0, bf_hi(d0.y), acc[3]);
        acc[4] = fmaf(a0, bf_lo(d0.z), acc[4]);
        acc[5] = fmaf(a0, bf_hi(d0.z), acc[5]);
        acc[6] = fmaf(a0, bf_lo(d0.w), acc[6]);
        acc[7] = fmaf(a0, bf_hi(d0.w), acc[7]);
    }

    #pragma unroll
    for (int off = LPR; off < 64; off <<= 1)
        #pragma unroll
        for (int j = 0; j < 8; ++j) acc[j] += __shfl_xor(acc[j], off, 64);

    if (lane < LPR) {
        float* dst = side + (size_t)h * DIN + q * 8;
        *(float4*)dst       = make_float4(acc[0], acc[1], acc[2], acc[3]);
        *(float4*)(dst + 4) = make_float4(acc[4], acc[5], acc[6], acc[7]);
    }
}

// ---------------------------------------------------------------------------
// transform_k: tiled vector GEMM. ego_in is bf16 (or fp32 user/ent when
// CONCAT). Output bf16 (OUT_BF) or fp32.  (R2-verified structure.)
// ---------------------------------------------------------------------------
template<int DIN, int DOUT, int TILE_ROWS, bool CONCAT, bool OUT_BF>
__global__ __launch_bounds__(256)
void transform_k(const unsigned short* __restrict__ ego_in,
                 const float* __restrict__ user_emb, const float* __restrict__ ent_emb,
                 const float* __restrict__ side,
                 const float* __restrict__ Wgc, const float* __restrict__ bgc,
                 const float* __restrict__ Wbi, const float* __restrict__ bbi,
                 void* __restrict__ ego_out) {
    constexpr int NG = DOUT / 8;
    constexpr int RG = 256 / NG;
    constexpr int RT = TILE_ROWS / RG;
    constexpr int STRIDE = DIN + 4;
    constexpr int KC8 = DIN / 8;

    __shared__ float sWgc[DIN * DOUT], sWbi[DIN * DOUT];
    __shared__ float sU[TILE_ROWS * STRIDE], sV[TILE_ROWS * STRIDE];

    int t = threadIdx.x;

    for (int i = t * 4; i < DIN * DOUT; i += 1024) {
        *(float4*)&sWgc[i] = *(const float4*)&Wgc[i];
        *(float4*)&sWbi[i] = *(const float4*)&Wbi[i];
    }

    int base = blockIdx.x * TILE_ROWS;
    for (int f = t; f < TILE_ROWS * KC8; f += 256) {
        int row = f / KC8, c8 = f % KC8;
        int n = base + row;
        int nc = n < N_NODES ? n : N_NODES - 1;
        float ev[8];
        if (CONCAT) {
            const float* erow = (nc < N_USERS) ? user_emb + (size_t)nc * 64
                                               : ent_emb + (size_t)(nc - N_USERS) * 64;
            float4 a = *(const float4*)(erow + c8 * 8);
            float4 b = *(const float4*)(erow + c8 * 8 + 4);
            ev[0] = a.x; ev[1] = a.y; ev[2] = a.z; ev[3] = a.w;
            ev[4] = b.x; ev[5] = b.y; ev[6] = b.z; ev[7] = b.w;
        } else {
            uint4 d = *(const uint4*)(ego_in + (size_t)nc * DIN + c8 * 8);
            ev[0] = bf_lo(d.x); ev[1] = bf_hi(d.x);
            ev[2] = bf_lo(d.y); ev[3] = bf_hi(d.y);
            ev[4] = bf_lo(d.z); ev[5] = bf_hi(d.z);
            ev[6] = bf_lo(d.w); ev[7] = bf_hi(d.w);
        }
        const float* srow = side + (size_t)nc * DIN + c8 * 8;
        float4 s0 = *(const float4*)srow;
        float4 s1 = *(const float4*)(srow + 4);
        float sv8[8] = {s0.x, s0.y, s0.z, s0.w, s1.x, s1.y, s1.z, s1.w};
        float* pu = &sU[row * STRIDE + c8 * 8];
        float* pv = &sV[row * STRIDE + c8 * 8];
        *(float4*)pu       = make_float4(ev[0] + sv8[0], ev[1] + sv8[1], ev[2] + sv8[2], ev[3] + sv8[3]);
        *(float4*)(pu + 4) = make_float4(ev[4] + sv8[4], ev[5] + sv8[5], ev[6] + sv8[6], ev[7] + sv8[7]);
        *(float4*)pv       = make_float4(ev[0] * sv8[0], ev[1] * sv8[1], ev[2] * sv8[2], ev[3] * sv8[3]);
        *(float4*)(pv + 4) = make_float4(ev[4] * sv8[4], ev[5] * sv8[5], ev[6] * sv8[6], ev[7] * sv8[7]);
    }
    __syncthreads();

    int cg = t % NG, rgi = t / NG;
    int c0 = cg * 8;
    int r0 = rgi * RT;

    float accg[RT][8], accb[RT][8];
    #pragma unroll
    for (int r = 0; r < RT; ++r)
        #pragma unroll
        for (int j = 0; j < 8; ++j) { accg[r][j] = 0.f; accb[r][j] = 0.f; }

    for (int k = 0; k < DIN; k += 4) {
        float4 u4[RT], v4[RT];
        #pragma unroll
        for (int r = 0; r < RT; ++r) {
            u4[r] = *(const float4*)&sU[(r0 + r) * STRIDE + k];
            v4[r] = *(const float4*)&sV[(r0 + r) * STRIDE + k];
        }
        #pragma unroll
        for (int kk = 0; kk < 4; ++kk) {
            float4 wg0 = *(const float4*)&sWgc[(k + kk) * DOUT + c0];
            float4 wg1 = *(const float4*)&sWgc[(k + kk) * DOUT + c0 + 4];
            float4 wb0 = *(const float4*)&sWbi[(k + kk) * DOUT + c0];
            float4 wb1 = *(const float4*)&sWbi[(k + kk) * DOUT + c0 + 4];
            #pragma unroll
            for (int r = 0; r < RT; ++r) {
                float u = ((const float*)&u4[r])[kk];
                float v = ((const float*)&v4[r])[kk];
                accg[r][0] = fmaf(u, wg0.x, accg[r][0]);
                accg[r][1] = fmaf(u, wg0.y, accg[r][1]);
                accg[r][2] = fmaf(u, wg0.z, accg[r][2]);
                accg[r][3] = fmaf(u, wg0.w, accg[r][3]);
                accg[r][4] = fmaf(u, wg1.x, accg[r][4]);
                accg[r][5] = fmaf(u, wg1.y, accg[r][5]);
                accg[r][6] = fmaf(u, wg1.z, accg[r][6]);
                accg[r][7] = fmaf(u, wg1.w, accg[r][7]);
                accb[r][0] = fmaf(v, wb0.x, accb[r][0]);
                accb[r][1] = fmaf(v, wb0.y, accb[r][1]);
                accb[r][2] = fmaf(v, wb0.z, accb[r][2]);
                accb[r][3] = fmaf(v, wb0.w, accb[r][3]);
                accb[r][4] = fmaf(v, wb1.x, accb[r][4]);
                accb[r][5] = fmaf(v, wb1.y, accb[r][5]);
                accb[r][6] = fmaf(v, wb1.z, accb[r][6]);
                accb[r][7] = fmaf(v, wb1.w, accb[r][7]);
            }
        }
    }

    float4 bg0 = *(const float4*)&bgc[c0];
    float4 bg1 = *(const float4*)&bgc[c0 + 4];
    float4 bb0 = *(const float4*)&bbi[c0];
    float4 bb1 = *(const float4*)&bbi[c0 + 4];
    float bg[8] = {bg0.x, bg0.y, bg0.z, bg0.w, bg1.x, bg1.y, bg1.z, bg1.w};
    float bb[8] = {bb0.x, bb0.y, bb0.z, bb0.w, bb1.x, bb1.y, bb1.z, bb1.w};

    #pragma unroll
    for (int r = 0; r < RT; ++r) {
        int n = base + r0 + r;
        if (n < N_NODES) {
            float o[8];
            #pragma unroll
            for (int j = 0; j < 8; ++j) {
                float gg = accg[r][j] + bg[j];
                float b2 = accb[r][j] + bb[j];
                gg = gg > 0.f ? gg : SLOPE * gg;
                b2 = b2 > 0.f ? b2 : SLOPE * b2;
                o[j] = gg + b2;
            }
            if (OUT_BF) {
                unsigned short* dst = (unsigned short*)ego_out + (size_t)n * DOUT + c0;
                uint4 wv;
                wv.x = f2bf(o[0]) | (f2bf(o[1]) << 16);
                wv.y = f2bf(o[2]) | (f2bf(o[3]) << 16);
                wv.z = f2bf(o[4]) | (f2bf(o[5]) << 16);
                wv.w = f2bf(o[6]) | (f2bf(o[7]) << 16);
                *(uint4*)dst = wv;
            } else {
                float* dst = (float*)ego_out + (size_t)n * DOUT + c0;
                *(float4*)dst       = make_float4(o[0], o[1], o[2], o[3]);
                *(float4*)(dst + 4) = make_float4(o[4], o[5], o[6], o[7]);
            }
        }
    }
}

// ---------------------------------------------------------------------------
// Gather: out rows = [ego0(64) | norm(ego1)(64) | norm(ego2)(32) | norm(ego3)(16)]
// 256-thread blocks, 4 rows/block (one wave each; shuffles are per-wave).
// ---------------------------------------------------------------------------
__global__ __launch_bounds__(256)
void gather_k(const int* __restrict__ users, const int* __restrict__ pos,
              const int* __restrict__ neg,
              const float* __restrict__ user_emb, const float* __restrict__ ent_emb,
              const unsigned short* __restrict__ ego1_bf,
              const unsigned short* __restrict__ ego2_bf,
              const float* __restrict__ ego3,
              float* __restrict__ out) {
    int w = threadIdx.x >> 6;
    int lane = threadIdx.x & 63;
    int r = blockIdx.x * 4 + w;
    int which = r / BATCH;
    int i = r - which * BATCH;
    int node;
    if (which == 0)      node = users[i];
    else if (which == 1) node = N_USERS + pos[i];
    else                 node = N_USERS + neg[i];

    float* o = out + (size_t)r * 176;

    float x0 = (node < N_USERS) ? user_emb[(size_t)node * 64 + lane]
                                : ent_emb[(size_t)(node - N_USERS) * 64 + lane];
    o[lane] = x0;

    float x1 = __uint_as_float((unsigned)ego1_bf[(size_t)node * 64 + lane] << 16);
    float ss = x1 * x1;
    #pragma unroll
    for (int off = 32; off > 0; off >>= 1) ss += __shfl_xor(ss, off, 64);
    o[64 + lane] = x1 / fmaxf(sqrtf(ss), EPSF);

    float x2 = (lane < 32)
        ? __uint_as_float((unsigned)ego2_bf[(size_t)node * 32 + lane] << 16) : 0.f;
    float ss2 = x2 * x2;
    #pragma unroll
    for (int off = 32; off > 0; off >>= 1) ss2 += __shfl_xor(ss2, off, 64);
    if (lane < 32) o[128 + lane] = x2 / fmaxf(sqrtf(ss2), EPSF);

    float x3 = (lane < 16) ? ego3[(size_t)node * 16 + lane] : 0.f;
    float ss3 = x3 * x3;
    #pragma unroll
    for (int off = 32; off > 0; off >>= 1) ss3 += __shfl_xor(ss3, off, 64);
    if (lane < 16) o[160 + lane] = x3 / fmaxf(sqrtf(ss3), EPSF);
}

// ---------------------------------------------------------------------------
extern "C" void kernel_launch(void* const* d_in, const int* in_sizes, int n_in,
                              void* d_out, int out_size, void* d_ws, size_t ws_size,
                              hipStream_t stream) {
    const int*   users    = (const int*)d_in[0];
    const int*   pos      = (const int*)d_in[1];
    const int*   neg      = (const int*)d_in[2];
    const int*   all_h    = (const int*)d_in[3];
    const int*   all_t    = (const int*)d_in[4];
    const float* A        = (const float*)d_in[5];
    const float* user_emb = (const float*)d_in[6];
    const float* ent_emb  = (const float*)d_in[7];
    const float* Wgc0 = (const float*)d_in[8];
    const float* bgc0 = (const float*)d_in[9];
    const float* Wbi0 = (const float*)d_in[10];
    const float* bbi0 = (const float*)d_in[11];
    const float* Wgc1 = (const float*)d_in[12];
    const float* bgc1 = (const float*)d_in[13];
    const float* Wbi1 = (const float*)d_in[14];
    const float* bbi1 = (const float*)d_in[15];
    const float* Wgc2 = (const float*)d_in[16];
    const float* bgc2 = (const float*)d_in[17];
    const float* Wbi2 = (const float*)d_in[18];
    const float* bbi2 = (const float*)d_in[19];

    // ---- workspace (256B-aligned). rec dead after side L2 -> ego3 aliases.
    char* p = (char*)d_ws;
    int*   gcursor = (int*)p;            p += ((size_t)NBUK * GC_STRIDE * 4 + 255) & ~255ull;
    int2*  rec     = (int2*)p;           char* rec_base = p;
    p += ((size_t)NBUK * STR * 8 + 255) & ~255ull;
    int2*  range   = (int2*)p;           p += ((size_t)N_NODES * 8 + 255) & ~255ull;
    float* side    = (float*)p;          p += ((size_t)N_NODES * 64 * 4 + 255) & ~255ull;
    unsigned short* ego0_bf = (unsigned short*)p; p += ((size_t)N_NODES * 64 * 2 + 255) & ~255ull;
    unsigned short* ego1_bf = (unsigned short*)p; p += ((size_t)N_NODES * 64 * 2 + 255) & ~255ull;
    unsigned short* ego2_bf = (unsigned short*)p; p += ((size_t)N_NODES * 32 * 2 + 255) & ~255ull;
    float* ego3    = (float*)rec_base;   // aliases rec (dead by then)
    float* out     = (float*)d_out;

    const int nodeBlocks = N_NODES / 4;

    // ---- prep: merged {bucket partition + bf16 cast} + local sort ----
    (void)hipMemsetAsync(gcursor, 0, (size_t)NBUK * GC_STRIDE * 4, stream);
    prep_k<<<NPB + CASTB, PBLK, 0, stream>>>(all_h, all_t, A, gcursor, rec,
                                             user_emb, ent_emb, ego0_bf);
    local_sort_k<<<NBUK, 256, 0, stream>>>(gcursor, rec, range);

    // ---- layer 0: 64 -> 64 ----
    side_k<64><<<nodeBlocks, 256, 0, stream>>>(range, rec, ego0_bf, side);
    transform_k<64, 64, 64, true, true><<<(N_NODES + 63) / 64, 256, 0, stream>>>(
        nullptr, user_emb, ent_emb, side, Wgc0, bgc0, Wbi0, bbi0, ego1_bf);

    // ---- layer 1: 64 -> 32 ----
    side_k<64><<<nodeBlocks, 256, 0, stream>>>(range, rec, ego1_bf, side);
    transform_k<64, 32, 64, false, true><<<(N_NODES + 63) / 64, 256, 0, stream>>>(
        ego1_bf, nullptr, nullptr, side, Wgc1, bgc1, Wbi1, bbi1, ego2_bf);

    // ---- layer 2: 32 -> 16 ----
    side_k<32><<<nodeBlocks, 256, 0, stream>>>(range, rec, ego2_bf, side);
    transform_k<32, 16, 128, false, false><<<(N_NODES + 127) / 128, 256, 0, stream>>>(
        ego2_bf, nullptr, nullptr, side, Wgc2, bgc2, Wbi2, bbi2, ego3);

    // ---- final gather + lazy normalization ----
    gather_k<<<3 * BATCH / 4, 256, 0, stream>>>(
        users, pos, neg, user_emb, ent_emb, ego1_bf, ego2_bf, ego3, out);
}

// Round 7
// 487.728 us; speedup vs baseline: 1.0153x; 1.0153x over previous
//
#include <hip/hip_runtime.h>
#include <math.h>

#define N_USERS    50000
#define N_ENTITIES 100000
#define N_NODES    150000
#define N_EDGES    3000000
#define BATCH      8192
#define SLOPE      0.2f
#define EPSF       1e-12f

// bucket partition: bucket = h>>6 (64 nodes per bucket)
#define NBUK   2344            // ceil(150000/64)
#define CAP    1536            // per-bucket real-record capacity (mean 1280, +7.1 sd)
#define STR    2560            // physical bucket stride: CAP + 64*16 padding worst case
#define PADM   16              // per-node segment padded to multiple of 16 edges
#define BLK_E  12288           // edges per partition block (12 per thread)
#define NPB    ((N_EDGES + BLK_E - 1) / BLK_E)   // 245
#define PBLK   1024            // partition block size (16 waves)
#define EPT    (BLK_E / PBLK)  // 12 edges per thread
#define CH     4096            // copy-out chunk (positions per LDS flush)
#define GC_STRIDE 16           // gcursor padded: 1 counter per 64B line
#define CASTB  ((N_NODES * 64 / 4 + PBLK - 1) / PBLK)   // 2344 cast blocks

__device__ __forceinline__ unsigned f2bf(float f) {       // RNE fp32->bf16
    unsigned u = __float_as_uint(f);
    return (u + 0x7FFFu + ((u >> 16) & 1u)) >> 16;
}
__device__ __forceinline__ float bf_lo(unsigned d) { return __uint_as_float(d << 16); }
// hi bf16 WITHOUT masking low bits: garbage adds <=2^-16 relative error,
// strictly dominated by the 2^-9 bf16 rounding already present.
__device__ __forceinline__ float bf_hi(unsigned d) { return __uint_as_float(d); }

// ---------------------------------------------------------------------------
// prep_k: merged partition (blocks < NPB) + bf16 cast (blocks >= NPB).
// The two are independent; merging lets cast0's streaming blocks co-schedule
// into partition's latency stalls instead of running serially after it.
// (R6-verified: merge+gather-batch saved ~14us of serial time.)
// Partition body = R2-verified register-staged bucket scatter.
// ---------------------------------------------------------------------------
__global__ __launch_bounds__(PBLK)
void prep_k(const int* __restrict__ all_h, const int* __restrict__ all_t,
            const float* __restrict__ A,
            int* __restrict__ gcursor, int2* __restrict__ rec,
            const float* __restrict__ user_emb, const float* __restrict__ ent_emb,
            unsigned short* __restrict__ ego0_bf) {
    __shared__ int pos[NBUK];      // counts -> excl starts -> cursors
    __shared__ int gofs[NBUK];     // global_base - local_start per bucket
    __shared__ int wsum[PBLK / 64];
    __shared__ int2 srec[CH];      // staged records for current chunk
    __shared__ int  sdst[CH];      // staged global slots (-1 = dropped)

    int t = threadIdx.x;

    if (blockIdx.x >= NPB) {
        // ---- cast body: concat(user,ent) -> bf16 table ----
        int idx = (blockIdx.x - NPB) * PBLK + t;
        const int total = N_NODES * 64 / 4;
        if (idx >= total) return;
        int ge = idx * 4;
        const float* src = (ge < N_USERS * 64) ? user_emb + ge
                                               : ent_emb + (ge - N_USERS * 64);
        float4 v = *(const float4*)src;
        ushort4 o;
        o.x = (unsigned short)f2bf(v.x);
        o.y = (unsigned short)f2bf(v.y);
        o.z = (unsigned short)f2bf(v.z);
        o.w = (unsigned short)f2bf(v.w);
        *(ushort4*)(ego0_bf + ge) = o;
        return;
    }

    // ---- partition body ----
    for (int i = t; i < NBUK; i += PBLK) pos[i] = 0;
    __syncthreads();

    int e0 = blockIdx.x * BLK_E;
    int e1 = e0 + BLK_E; if (e1 > N_EDGES) e1 = N_EDGES;
    int tot = e1 - e0;

    // single coalesced read of all three edge streams into registers
    int h[EPT]; int tt[EPT]; float aa[EPT];
    #pragma unroll
    for (int k = 0; k < EPT; ++k) {
        int e = e0 + k * PBLK + t;
        bool v = e < e1;
        h[k]  = v ? all_h[e] : -1;
        tt[k] = v ? all_t[e] : 0;
        aa[k] = v ? A[e] : 0.f;
    }
    #pragma unroll
    for (int k = 0; k < EPT; ++k)
        if (h[k] >= 0) atomicAdd(&pos[h[k] >> 6], 1);
    __syncthreads();

    // sweep 1: read own counts, reserve global space (padded counter lines)
    int c[3], g[3];
    int i0 = t * 3;
    int tsum = 0;
    #pragma unroll
    for (int j = 0; j < 3; ++j) {
        int idx = i0 + j;
        c[j] = (idx < NBUK) ? pos[idx] : 0;
        tsum += c[j];
        g[j] = (idx < NBUK && c[j]) ? atomicAdd(&gcursor[idx * GC_STRIDE], c[j]) : 0;
    }

    // block-wide exclusive scan of per-thread sums (16 waves of 64)
    int lane = t & 63, w = t >> 6;
    int incl = tsum;
    #pragma unroll
    for (int off = 1; off < 64; off <<= 1) {
        int x = __shfl_up(incl, off, 64);
        if (lane >= off) incl += x;
    }
    if (lane == 63) wsum[w] = incl;
    __syncthreads();
    int wbase = 0;
    for (int j = 0; j < w; ++j) wbase += wsum[j];
    int excl = wbase + (incl - tsum);

    // sweep 2: exclusive starts into pos; gofs folds global base - local start
    #pragma unroll
    for (int j = 0; j < 3; ++j) {
        int idx = i0 + j;
        if (idx < NBUK) { pos[idx] = excl; gofs[idx] = g[j] - excl; }
        excl += c[j];
    }
    __syncthreads();

    // placement: block-sorted position p + final global slot per edge (regs)
    int pp[EPT], gd[EPT];
    #pragma unroll
    for (int k = 0; k < EPT; ++k) {
        if (h[k] >= 0) {
            int b = h[k] >> 6;
            int p = atomicAdd(&pos[b], 1);
            pp[k] = p;
            int gr = gofs[b] + p;              // global rank within bucket
            gd[k] = (gr < CAP) ? b * STR + gr : -1;
        } else {
            pp[k] = -1; gd[k] = -1;
        }
    }

    // chunked reg->LDS scatter + linear coalesced flush
    for (int base = 0; base < tot; base += CH) {
        __syncthreads();                       // LDS chunk free (prev flush done)
        int lim = tot - base; if (lim > CH) lim = CH;
        #pragma unroll
        for (int k = 0; k < EPT; ++k) {
            int s = pp[k] - base;
            if (s >= 0 && s < CH) {
                srec[s] = make_int2(tt[k] | ((h[k] & 63) << 18), __float_as_int(aa[k]));
                sdst[s] = gd[k];
            }
        }
        __syncthreads();
        for (int s = t; s < lim; s += PBLK) {
            int d = sdst[s];
            if (d >= 0) rec[d] = srec[s];
        }
    }
}

// ---------------------------------------------------------------------------
// local_sort_k: per-bucket 64-bin counting sort in LDS -> h-grouped records,
// each node's segment PADDED to a multiple of PADM(16) with zero records
// {t=0, a=0}. Padding guarantees every 8/16-slot block a wave touches is
// initialized -> side_k needs only block-granular (wave-uniform) predicates.
// ---------------------------------------------------------------------------
__global__ __launch_bounds__(256)
void local_sort_k(const int* __restrict__ gcursor, int2* __restrict__ rec,
                  int2* __restrict__ range) {
    __shared__ int2 sin[CAP];
    __shared__ int2 sout[STR];
    __shared__ int cnt64[64];
    __shared__ int pos64[64];
    __shared__ int s_ptot;
    int b = blockIdx.x, t = threadIdx.x;
    int cnt = gcursor[(size_t)b * GC_STRIDE]; if (cnt > CAP) cnt = CAP;

    if (t < 64) cnt64[t] = 0;
    __syncthreads();

    for (int i = t; i < cnt; i += 256) {
        int2 p = rec[(size_t)b * STR + i];
        sin[i] = p;
        atomicAdd(&cnt64[(p.x >> 18) & 63], 1);
    }
    __syncthreads();

    if (t < 64) {
        int v = cnt64[t];
        int pv = (v + PADM - 1) & ~(PADM - 1);
        int sum = pv;
        #pragma unroll
        for (int off = 1; off < 64; off <<= 1) {
            int x = __shfl_up(sum, off, 64);
            if (t >= off) sum += x;
        }
        pos64[t] = sum - pv;
        if (t == 63) s_ptot = sum;
    }
    __syncthreads();
    int ptot = s_ptot;

    // zero padded region, then scatter real records into padded positions
    for (int i = t; i < ptot; i += 256) sout[i] = make_int2(0, 0);
    __syncthreads();

    for (int i = t; i < cnt; i += 256) {
        int2 p = sin[i];
        int l = (p.x >> 18) & 63;
        int dst = atomicAdd(&pos64[l], 1);
        sout[dst] = make_int2(p.x & 0x3FFFF, p.y);
    }
    __syncthreads();

    for (int i = t; i < ptot; i += 256)
        rec[(size_t)b * STR + i] = sout[i];

    if (t < 64) {
        int v = cnt64[t];
        int pv = (v + PADM - 1) & ~(PADM - 1);
        int sum = pv;
        #pragma unroll
        for (int off = 1; off < 64; off <<= 1) {
            int x = __shfl_up(sum, off, 64);
            if (t >= off) sum += x;
        }
        int start = b * STR + (sum - pv);
        int node = b * 64 + t;
        if (node < N_NODES) range[node] = make_int2(start, start + pv);
    }
}

// ---------------------------------------------------------------------------
// side_k: wave-per-node segment-sum over bf16 rows (R4-verified 63.3us form,
// plain int2 rec loads — R6's nontemporal variant cost +8us/pass, reverted).
// Ranges padded to multiple of 16 -> no bounds clamping. This is the measured
// rate limit for the random 128B table gather (R5 proved MLP isn't the
// bottleneck; FETCH = compulsory 8-XCD replication floor).
// ---------------------------------------------------------------------------
template<int DIN>
__global__ __launch_bounds__(256)
void side_k(const int2* __restrict__ range, const int2* __restrict__ rec,
            const unsigned short* __restrict__ tab, float* __restrict__ side) {
    constexpr int LPR = DIN / 8;       // 8 (D64), 4 (D32)
    constexpr int EPW = 64 / LPR;      // 8 (D64), 16 (D32)

    int w = threadIdx.x >> 6;
    int lane = threadIdx.x & 63;
    int h = blockIdx.x * 4 + w;

    int2 rg = range[h];
    int e0 = rg.x, e1 = rg.y;          // e1 - e0 is a multiple of 16
    int g = lane / LPR;
    int q = lane % LPR;

    float acc[8];
    #pragma unroll
    for (int j = 0; j < 8; ++j) acc[j] = 0.f;

    int e = e0;
    for (; e + 2 * EPW <= e1; e += 2 * EPW) {
        int2 p0 = rec[e + g];
        int2 p1 = rec[e + EPW + g];
        float a0 = __int_as_float(p0.y);
        float a1 = __int_as_float(p1.y);
        uint4 d0 = *(const uint4*)(tab + (unsigned)(p0.x * DIN) + q * 8);
        uint4 d1 = *(const uint4*)(tab + (unsigned)(p1.x * DIN) + q * 8);
        acc[0] = fmaf(a0, bf_lo(d0.x), acc[0]);
        acc[1] = fmaf(a0, bf_hi(d0.x), acc[1]);
        acc[2] = fmaf(a0, bf_lo(d0.y), acc[2]);
        acc[3] = fmaf(a0, bf_hi(d0.y), acc[3]);
        acc[4] = fmaf(a0, bf_lo(d0.z), acc[4]);
        acc[5] = fmaf(a0, bf_hi(d0.z), acc[5]);
        acc[6] = fmaf(a0, bf_lo(d0.w), acc[6]);
        acc[7] = fmaf(a0, bf_hi(d0.w), acc[7]);
        acc[0] = fmaf(a1, bf_lo(d1.x), acc[0]);
        acc[1] = fmaf(a1, bf_hi(d1.x), acc[1]);
        acc[2] = fmaf(a1, bf_lo(d1.y), acc[2]);
        acc[3] = fmaf(a1, bf_hi(d1.y), acc[3]);
        acc[4] = fmaf(a1, bf_lo(d1.z), acc[4]);
        acc[5] = fmaf(a1, bf_hi(d1.z), acc[5]);
        acc[6] = fmaf(a1, bf_lo(d1.w), acc[6]);
        acc[7] = fmaf(a1, bf_hi(d1.w), acc[7]);
    }
    if (e < e1) {                      // remainder is exactly EPW (D32 only)
        int2 p0 = rec[e + g];
        float a0 = __int_as_float(p0.y);
        uint4 d0 = *(const uint4*)(tab + (unsigned)(p0.x * DIN) + q * 8);
        acc[0] = fmaf(a0, bf_lo(d0.x), acc[0]);
        acc[1] = fmaf(a0, bf_hi(d0.x), acc[1]);
        acc[2] = fmaf(a0, bf_lo(d0.y), acc[2]);
        acc[3] = fmaf(a0, bf_hi(d0.y), acc[3]);
        acc[4] = fmaf(a0, bf_lo(d0.z), acc[4]);
        acc[5] = fmaf(a0, bf_hi(d0.z), acc[5]);
        acc[6] = fmaf(a0, bf_lo(d0.w), acc[6]);
        acc[7] = fmaf(a0, bf_hi(d0.w), acc[7]);
    }

    #pragma unroll
    for (int off = LPR; off < 64; off <<= 1)
        #pragma unroll
        for (int j = 0; j < 8; ++j) acc[j] += __shfl_xor(acc[j], off, 64);

    if (lane < LPR) {
        float* dst = side + (size_t)h * DIN + q * 8;
        *(float4*)dst       = make_float4(acc[0], acc[1], acc[2], acc[3]);
        *(float4*)(dst + 4) = make_float4(acc[4], acc[5], acc[6], acc[7]);
    }
}

// ---------------------------------------------------------------------------
// transform_k: tiled vector GEMM. ego_in is bf16 (or fp32 user/ent when
// CONCAT). Output bf16 (OUT_BF) or fp32.  (R2-verified structure.)
// ---------------------------------------------------------------------------
template<int DIN, int DOUT, int TILE_ROWS, bool CONCAT, bool OUT_BF>
__global__ __launch_bounds__(256)
void transform_k(const unsigned short* __restrict__ ego_in,
                 const float* __restrict__ user_emb, const float* __restrict__ ent_emb,
                 const float* __restrict__ side,
                 const float* __restrict__ Wgc, const float* __restrict__ bgc,
                 const float* __restrict__ Wbi, const float* __restrict__ bbi,
                 void* __restrict__ ego_out) {
    constexpr int NG = DOUT / 8;
    constexpr int RG = 256 / NG;
    constexpr int RT = TILE_ROWS / RG;
    constexpr int STRIDE = DIN + 4;
    constexpr int KC8 = DIN / 8;

    __shared__ float sWgc[DIN * DOUT], sWbi[DIN * DOUT];
    __shared__ float sU[TILE_ROWS * STRIDE], sV[TILE_ROWS * STRIDE];

    int t = threadIdx.x;

    for (int i = t * 4; i < DIN * DOUT; i += 1024) {
        *(float4*)&sWgc[i] = *(const float4*)&Wgc[i];
        *(float4*)&sWbi[i] = *(const float4*)&Wbi[i];
    }

    int base = blockIdx.x * TILE_ROWS;
    for (int f = t; f < TILE_ROWS * KC8; f += 256) {
        int row = f / KC8, c8 = f % KC8;
        int n = base + row;
        int nc = n < N_NODES ? n : N_NODES - 1;
        float ev[8];
        if (CONCAT) {
            const float* erow = (nc < N_USERS) ? user_emb + (size_t)nc * 64
                                               : ent_emb + (size_t)(nc - N_USERS) * 64;
            float4 a = *(const float4*)(erow + c8 * 8);
            float4 b = *(const float4*)(erow + c8 * 8 + 4);
            ev[0] = a.x; ev[1] = a.y; ev[2] = a.z; ev[3] = a.w;
            ev[4] = b.x; ev[5] = b.y; ev[6] = b.z; ev[7] = b.w;
        } else {
            uint4 d = *(const uint4*)(ego_in + (size_t)nc * DIN + c8 * 8);
            ev[0] = bf_lo(d.x); ev[1] = bf_hi(d.x);
            ev[2] = bf_lo(d.y); ev[3] = bf_hi(d.y);
            ev[4] = bf_lo(d.z); ev[5] = bf_hi(d.z);
            ev[6] = bf_lo(d.w); ev[7] = bf_hi(d.w);
        }
        const float* srow = side + (size_t)nc * DIN + c8 * 8;
        float4 s0 = *(const float4*)srow;
        float4 s1 = *(const float4*)(srow + 4);
        float sv8[8] = {s0.x, s0.y, s0.z, s0.w, s1.x, s1.y, s1.z, s1.w};
        float* pu = &sU[row * STRIDE + c8 * 8];
        float* pv = &sV[row * STRIDE + c8 * 8];
        *(float4*)pu       = make_float4(ev[0] + sv8[0], ev[1] + sv8[1], ev[2] + sv8[2], ev[3] + sv8[3]);
        *(float4*)(pu + 4) = make_float4(ev[4] + sv8[4], ev[5] + sv8[5], ev[6] + sv8[6], ev[7] + sv8[7]);
        *(float4*)pv       = make_float4(ev[0] * sv8[0], ev[1] * sv8[1], ev[2] * sv8[2], ev[3] * sv8[3]);
        *(float4*)(pv + 4) = make_float4(ev[4] * sv8[4], ev[5] * sv8[5], ev[6] * sv8[6], ev[7] * sv8[7]);
    }
    __syncthreads();

    int cg = t % NG, rgi = t / NG;
    int c0 = cg * 8;
    int r0 = rgi * RT;

    float accg[RT][8], accb[RT][8];
    #pragma unroll
    for (int r = 0; r < RT; ++r)
        #pragma unroll
        for (int j = 0; j < 8; ++j) { accg[r][j] = 0.f; accb[r][j] = 0.f; }

    for (int k = 0; k < DIN; k += 4) {
        float4 u4[RT], v4[RT];
        #pragma unroll
        for (int r = 0; r < RT; ++r) {
            u4[r] = *(const float4*)&sU[(r0 + r) * STRIDE + k];
            v4[r] = *(const float4*)&sV[(r0 + r) * STRIDE + k];
        }
        #pragma unroll
        for (int kk = 0; kk < 4; ++kk) {
            float4 wg0 = *(const float4*)&sWgc[(k + kk) * DOUT + c0];
            float4 wg1 = *(const float4*)&sWgc[(k + kk) * DOUT + c0 + 4];
            float4 wb0 = *(const float4*)&sWbi[(k + kk) * DOUT + c0];
            float4 wb1 = *(const float4*)&sWbi[(k + kk) * DOUT + c0 + 4];
            #pragma unroll
            for (int r = 0; r < RT; ++r) {
                float u = ((const float*)&u4[r])[kk];
                float v = ((const float*)&v4[r])[kk];
                accg[r][0] = fmaf(u, wg0.x, accg[r][0]);
                accg[r][1] = fmaf(u, wg0.y, accg[r][1]);
                accg[r][2] = fmaf(u, wg0.z, accg[r][2]);
                accg[r][3] = fmaf(u, wg0.w, accg[r][3]);
                accg[r][4] = fmaf(u, wg1.x, accg[r][4]);
                accg[r][5] = fmaf(u, wg1.y, accg[r][5]);
                accg[r][6] = fmaf(u, wg1.z, accg[r][6]);
                accg[r][7] = fmaf(u, wg1.w, accg[r][7]);
                accb[r][0] = fmaf(v, wb0.x, accb[r][0]);
                accb[r][1] = fmaf(v, wb0.y, accb[r][1]);
                accb[r][2] = fmaf(v, wb0.z, accb[r][2]);
                accb[r][3] = fmaf(v, wb0.w, accb[r][3]);
                accb[r][4] = fmaf(v, wb1.x, accb[r][4]);
                accb[r][5] = fmaf(v, wb1.y, accb[r][5]);
                accb[r][6] = fmaf(v, wb1.z, accb[r][6]);
                accb[r][7] = fmaf(v, wb1.w, accb[r][7]);
            }
        }
    }

    float4 bg0 = *(const float4*)&bgc[c0];
    float4 bg1 = *(const float4*)&bgc[c0 + 4];
    float4 bb0 = *(const float4*)&bbi[c0];
    float4 bb1 = *(const float4*)&bbi[c0 + 4];
    float bg[8] = {bg0.x, bg0.y, bg0.z, bg0.w, bg1.x, bg1.y, bg1.z, bg1.w};
    float bb[8] = {bb0.x, bb0.y, bb0.z, bb0.w, bb1.x, bb1.y, bb1.z, bb1.w};

    #pragma unroll
    for (int r = 0; r < RT; ++r) {
        int n = base + r0 + r;
        if (n < N_NODES) {
            float o[8];
            #pragma unroll
            for (int j = 0; j < 8; ++j) {
                float gg = accg[r][j] + bg[j];
                float b2 = accb[r][j] + bb[j];
                gg = gg > 0.f ? gg : SLOPE * gg;
                b2 = b2 > 0.f ? b2 : SLOPE * b2;
                o[j] = gg + b2;
            }
            if (OUT_BF) {
                unsigned short* dst = (unsigned short*)ego_out + (size_t)n * DOUT + c0;
                uint4 wv;
                wv.x = f2bf(o[0]) | (f2bf(o[1]) << 16);
                wv.y = f2bf(o[2]) | (f2bf(o[3]) << 16);
                wv.z = f2bf(o[4]) | (f2bf(o[5]) << 16);
                wv.w = f2bf(o[6]) | (f2bf(o[7]) << 16);
                *(uint4*)dst = wv;
            } else {
                float* dst = (float*)ego_out + (size_t)n * DOUT + c0;
                *(float4*)dst       = make_float4(o[0], o[1], o[2], o[3]);
                *(float4*)(dst + 4) = make_float4(o[4], o[5], o[6], o[7]);
            }
        }
    }
}

// ---------------------------------------------------------------------------
// Gather: out rows = [ego0(64) | norm(ego1)(64) | norm(ego2)(32) | norm(ego3)(16)]
// 256-thread blocks, 4 rows/block (one wave each; shuffles are per-wave).
// ---------------------------------------------------------------------------
__global__ __launch_bounds__(256)
void gather_k(const int* __restrict__ users, const int* __restrict__ pos,
              const int* __restrict__ neg,
              const float* __restrict__ user_emb, const float* __restrict__ ent_emb,
              const unsigned short* __restrict__ ego1_bf,
              const unsigned short* __restrict__ ego2_bf,
              const float* __restrict__ ego3,
              float* __restrict__ out) {
    int w = threadIdx.x >> 6;
    int lane = threadIdx.x & 63;
    int r = blockIdx.x * 4 + w;
    int which = r / BATCH;
    int i = r - which * BATCH;
    int node;
    if (which == 0)      node = users[i];
    else if (which == 1) node = N_USERS + pos[i];
    else                 node = N_USERS + neg[i];

    float* o = out + (size_t)r * 176;

    float x0 = (node < N_USERS) ? user_emb[(size_t)node * 64 + lane]
                                : ent_emb[(size_t)(node - N_USERS) * 64 + lane];
    o[lane] = x0;

    float x1 = __uint_as_float((unsigned)ego1_bf[(size_t)node * 64 + lane] << 16);
    float ss = x1 * x1;
    #pragma unroll
    for (int off = 32; off > 0; off >>= 1) ss += __shfl_xor(ss, off, 64);
    o[64 + lane] = x1 / fmaxf(sqrtf(ss), EPSF);

    float x2 = (lane < 32)
        ? __uint_as_float((unsigned)ego2_bf[(size_t)node * 32 + lane] << 16) : 0.f;
    float ss2 = x2 * x2;
    #pragma unroll
    for (int off = 32; off > 0; off >>= 1) ss2 += __shfl_xor(ss2, off, 64);
    if (lane < 32) o[128 + lane] = x2 / fmaxf(sqrtf(ss2), EPSF);

    float x3 = (lane < 16) ? ego3[(size_t)node * 16 + lane] : 0.f;
    float ss3 = x3 * x3;
    #pragma unroll
    for (int off = 32; off > 0; off >>= 1) ss3 += __shfl_xor(ss3, off, 64);
    if (lane < 16) o[160 + lane] = x3 / fmaxf(sqrtf(ss3), EPSF);
}

// ---------------------------------------------------------------------------
extern "C" void kernel_launch(void* const* d_in, const int* in_sizes, int n_in,
                              void* d_out, int out_size, void* d_ws, size_t ws_size,
                              hipStream_t stream) {
    const int*   users    = (const int*)d_in[0];
    const int*   pos      = (const int*)d_in[1];
    const int*   neg      = (const int*)d_in[2];
    const int*   all_h    = (const int*)d_in[3];
    const int*   all_t    = (const int*)d_in[4];
    const float* A        = (const float*)d_in[5];
    const float* user_emb = (const float*)d_in[6];
    const float* ent_emb  = (const float*)d_in[7];
    const float* Wgc0 = (const float*)d_in[8];
    const float* bgc0 = (const float*)d_in[9];
    const float* Wbi0 = (const float*)d_in[10];
    const float* bbi0 = (const float*)d_in[11];
    const float* Wgc1 = (const float*)d_in[12];
    const float* bgc1 = (const float*)d_in[13];
    const float* Wbi1 = (const float*)d_in[14];
    const float* bbi1 = (const float*)d_in[15];
    const float* Wgc2 = (const float*)d_in[16];
    const float* bgc2 = (const float*)d_in[17];
    const float* Wbi2 = (const float*)d_in[18];
    const float* bbi2 = (const float*)d_in[19];

    // ---- workspace (256B-aligned). rec dead after side L2 -> ego3 aliases.
    char* p = (char*)d_ws;
    int*   gcursor = (int*)p;            p += ((size_t)NBUK * GC_STRIDE * 4 + 255) & ~255ull;
    int2*  rec     = (int2*)p;           char* rec_base = p;
    p += ((size_t)NBUK * STR * 8 + 255) & ~255ull;
    int2*  range   = (int2*)p;           p += ((size_t)N_NODES * 8 + 255) & ~255ull;
    float* side    = (float*)p;          p += ((size_t)N_NODES * 64 * 4 + 255) & ~255ull;
    unsigned short* ego0_bf = (unsigned short*)p; p += ((size_t)N_NODES * 64 * 2 + 255) & ~255ull;
    unsigned short* ego1_bf = (unsigned short*)p; p += ((size_t)N_NODES * 64 * 2 + 255) & ~255ull;
    unsigned short* ego2_bf = (unsigned short*)p; p += ((size_t)N_NODES * 32 * 2 + 255) & ~255ull;
    float* ego3    = (float*)rec_base;   // aliases rec (dead by then)
    float* out     = (float*)d_out;

    const int nodeBlocks = N_NODES / 4;

    // ---- prep: merged {bucket partition + bf16 cast} + local sort ----
    (void)hipMemsetAsync(gcursor, 0, (size_t)NBUK * GC_STRIDE * 4, stream);
    prep_k<<<NPB + CASTB, PBLK, 0, stream>>>(all_h, all_t, A, gcursor, rec,
                                             user_emb, ent_emb, ego0_bf);
    local_sort_k<<<NBUK, 256, 0, stream>>>(gcursor, rec, range);

    // ---- layer 0: 64 -> 64 ----
    side_k<64><<<nodeBlocks, 256, 0, stream>>>(range, rec, ego0_bf, side);
    transform_k<64, 64, 64, true, true><<<(N_NODES + 63) / 64, 256, 0, stream>>>(
        nullptr, user_emb, ent_emb, side, Wgc0, bgc0, Wbi0, bbi0, ego1_bf);

    // ---- layer 1: 64 -> 32 ----
    side_k<64><<<nodeBlocks, 256, 0, stream>>>(range, rec, ego1_bf, side);
    transform_k<64, 32, 64, false, true><<<(N_NODES + 63) / 64, 256, 0, stream>>>(
        ego1_bf, nullptr, nullptr, side, Wgc1, bgc1, Wbi1, bbi1, ego2_bf);

    // ---- layer 2: 32 -> 16 ----
    side_k<32><<<nodeBlocks, 256, 0, stream>>>(range, rec, ego2_bf, side);
    transform_k<32, 16, 128, false, false><<<(N_NODES + 127) / 128, 256, 0, stream>>>(
        ego2_bf, nullptr, nullptr, side, Wgc2, bgc2, Wbi2, bbi2, ego3);

    // ---- final gather + lazy normalization ----
    gather_k<<<3 * BATCH / 4, 256, 0, stream>>>(
        users, pos, neg, user_emb, ent_emb, ego1_bf, ego2_bf, ego3, out);
}

// Round 8
// 476.633 us; speedup vs baseline: 1.0389x; 1.0233x over previous
//
#include <hip/hip_runtime.h>
#include <math.h>

#define N_USERS    50000
#define N_ENTITIES 100000
#define N_NODES    150000
#define N_EDGES    3000000
#define BATCH      8192
#define SLOPE      0.2f
#define EPSF       1e-12f

// bucket partition: bucket = h>>6 (64 nodes per bucket)
#define NBUK   2344            // ceil(150000/64)
#define CAP    1536            // per-bucket real-record capacity (mean 1280, +7.1 sd)
#define STR    2560            // physical bucket stride: CAP + 64*16 padding worst case
#define PADM   16              // per-node segment padded to multiple of 16 edges
#define BLK_E  12288           // edges per partition block (12 per thread)
#define NPB    ((N_EDGES + BLK_E - 1) / BLK_E)   // 245
#define PBLK   1024            // partition block size (16 waves)
#define EPT    (BLK_E / PBLK)  // 12 edges per thread
#define CH     4096            // copy-out chunk (positions per LDS flush)
#define PFW    (NBUK + 1)      // prefix row width (per-block exclusive starts + total)
#define CASTB  ((N_NODES * 64 / 4 + PBLK - 1) / PBLK)   // 2344 cast blocks

__device__ __forceinline__ unsigned f2bf(float f) {       // RNE fp32->bf16
    unsigned u = __float_as_uint(f);
    return (u + 0x7FFFu + ((u >> 16) & 1u)) >> 16;
}
__device__ __forceinline__ float bf_lo(unsigned d) { return __uint_as_float(d << 16); }
// hi bf16 WITHOUT masking low bits: garbage adds <=2^-16 relative error,
// strictly dominated by the 2^-9 bf16 rounding already present.
__device__ __forceinline__ float bf_hi(unsigned d) { return __uint_as_float(d); }

// ---------------------------------------------------------------------------
// prep_k: merged {partition -> block-contiguous staged records} + bf16 cast.
// R7 evidence: 68us with all pipes idle; cost = 573K device-scope gcursor
// atomics + ~25MB partial-line RMW on the bucket-shared scatter (WRITE 71MB
// vs 46MB payload) + memset feeding it. This version writes each block's
// bucket-sorted records BLOCK-CONTIGUOUSLY (rec_src, perfectly coalesced
// 16B stores, permutation -> every slot full, no sdst) and its per-bucket
// exclusive starts to prefix[block][0..NBUK] (9.4KB coalesced).
// No global atomics, no RMW, no gcursor, no memset dispatch.
// Cast body (blocks >= NPB) unchanged.
// ---------------------------------------------------------------------------
__global__ __launch_bounds__(PBLK)
void prep_k(const int* __restrict__ all_h, const int* __restrict__ all_t,
            const float* __restrict__ A,
            int* __restrict__ prefix, int2* __restrict__ rec_src,
            const float* __restrict__ user_emb, const float* __restrict__ ent_emb,
            unsigned short* __restrict__ ego0_bf) {
    __shared__ int pos[NBUK];      // counts -> excl starts -> cursors
    __shared__ int wsum[PBLK / 64];
    __shared__ int2 srec[CH];      // staged records for current chunk

    int t = threadIdx.x;

    if (blockIdx.x >= NPB) {
        // ---- cast body: concat(user,ent) -> bf16 table ----
        int idx = (blockIdx.x - NPB) * PBLK + t;
        const int total = N_NODES * 64 / 4;
        if (idx >= total) return;
        int ge = idx * 4;
        const float* src = (ge < N_USERS * 64) ? user_emb + ge
                                               : ent_emb + (ge - N_USERS * 64);
        float4 v = *(const float4*)src;
        ushort4 o;
        o.x = (unsigned short)f2bf(v.x);
        o.y = (unsigned short)f2bf(v.y);
        o.z = (unsigned short)f2bf(v.z);
        o.w = (unsigned short)f2bf(v.w);
        *(ushort4*)(ego0_bf + ge) = o;
        return;
    }

    // ---- partition body ----
    for (int i = t; i < NBUK; i += PBLK) pos[i] = 0;
    __syncthreads();

    int e0 = blockIdx.x * BLK_E;
    int e1 = e0 + BLK_E; if (e1 > N_EDGES) e1 = N_EDGES;
    int tot = e1 - e0;

    // single coalesced read of all three edge streams into registers
    int h[EPT]; int tt[EPT]; float aa[EPT];
    #pragma unroll
    for (int k = 0; k < EPT; ++k) {
        int e = e0 + k * PBLK + t;
        bool v = e < e1;
        h[k]  = v ? all_h[e] : -1;
        tt[k] = v ? all_t[e] : 0;
        aa[k] = v ? A[e] : 0.f;
    }
    #pragma unroll
    for (int k = 0; k < EPT; ++k)
        if (h[k] >= 0) atomicAdd(&pos[h[k] >> 6], 1);
    __syncthreads();

    // sweep 1: read own bucket counts
    int c[3];
    int i0 = t * 3;
    int tsum = 0;
    #pragma unroll
    for (int j = 0; j < 3; ++j) {
        int idx = i0 + j;
        c[j] = (idx < NBUK) ? pos[idx] : 0;
        tsum += c[j];
    }

    // block-wide exclusive scan of per-thread sums (16 waves of 64)
    int lane = t & 63, w = t >> 6;
    int incl = tsum;
    #pragma unroll
    for (int off = 1; off < 64; off <<= 1) {
        int x = __shfl_up(incl, off, 64);
        if (lane >= off) incl += x;
    }
    if (lane == 63) wsum[w] = incl;
    __syncthreads();   // also fences all sweep-1 pos[] reads before overwrite
    int wbase = 0;
    for (int j = 0; j < w; ++j) wbase += wsum[j];
    int excl = wbase + (incl - tsum);

    // sweep 2: exclusive starts into pos AND into this block's prefix row
    size_t prow = (size_t)blockIdx.x * PFW;
    #pragma unroll
    for (int j = 0; j < 3; ++j) {
        int idx = i0 + j;
        if (idx < NBUK) { pos[idx] = excl; prefix[prow + idx] = excl; }
        excl += c[j];
    }
    if (t == PBLK - 1) prefix[prow + NBUK] = excl;   // == tot (total real count)
    __syncthreads();

    // placement: block-sorted position per edge (permutation of [0,tot))
    int pp[EPT];
    #pragma unroll
    for (int k = 0; k < EPT; ++k)
        pp[k] = (h[k] >= 0) ? atomicAdd(&pos[h[k] >> 6], 1) : -1;

    // chunked reg->LDS scatter + LINEAR block-contiguous flush (16B stores)
    for (int base = 0; base < tot; base += CH) {
        __syncthreads();                       // LDS chunk free (prev flush done)
        int lim = tot - base; if (lim > CH) lim = CH;
        #pragma unroll
        for (int k = 0; k < EPT; ++k) {
            int s = pp[k] - base;
            if (s >= 0 && s < CH)
                srec[s] = make_int2(tt[k] | ((h[k] & 63) << 18), __float_as_int(aa[k]));
        }
        __syncthreads();
        // every slot [0,lim) is filled (pp is a permutation); lim is even
        const int4* s4 = (const int4*)srec;
        int4* d4 = (int4*)(rec_src + e0 + base);
        int lim2 = lim >> 1;
        for (int s = t; s < lim2; s += PBLK) d4[s] = s4[s];
    }
}

// ---------------------------------------------------------------------------
// local_sort_k: assemble bucket b from the 245 block-local runs (thread t
// owns run t via prefix[t][b..b+1]; 256-wide scan gives LDS destinations),
// then the R7-verified 64-bin counting sort: pad each node's segment to a
// multiple of PADM(16) with zero records {t=0,a=0}, write bucket-contiguous
// rec + per-node ranges. CAP drop-set preserved at the copy.
// ---------------------------------------------------------------------------
__global__ __launch_bounds__(256)
void local_sort_k(const int* __restrict__ prefix, const int2* __restrict__ rec_src,
                  int2* __restrict__ rec, int2* __restrict__ range) {
    __shared__ int2 sin[CAP];
    __shared__ int2 sout[STR];
    __shared__ int cnt64[64];
    __shared__ int pos64[64];
    __shared__ int sc[256];
    __shared__ int s_ptot;
    int b = blockIdx.x, t = threadIdx.x;

    if (t < 64) cnt64[t] = 0;

    // run t = this bucket's records inside prep block t's chunk
    int rstart = 0, n_t = 0;
    if (t < NPB) {
        const int* prow = prefix + (size_t)t * PFW + b;
        int s0 = prow[0];
        int s1 = prow[1];
        rstart = t * BLK_E + s0;
        n_t = s1 - s0;
    }
    sc[t] = n_t;
    __syncthreads();

    // 256-wide inclusive scan (Hillis-Steele, double barrier)
    for (int off = 1; off < 256; off <<= 1) {
        int v = sc[t];
        int u = (t >= off) ? sc[t - off] : 0;
        __syncthreads();
        sc[t] = v + u;
        __syncthreads();
    }
    int cnt = sc[255]; if (cnt > CAP) cnt = CAP;

    // gather this thread's run into sin + histogram by h&63
    if (t < NPB && n_t > 0) {
        int d = sc[t] - n_t;
        for (int j = 0; j < n_t; ++j) {
            int dj = d + j;
            if (dj >= CAP) break;
            int2 p = rec_src[rstart + j];
            sin[dj] = p;
            atomicAdd(&cnt64[(p.x >> 18) & 63], 1);
        }
    }
    __syncthreads();

    if (t < 64) {
        int v = cnt64[t];
        int pv = (v + PADM - 1) & ~(PADM - 1);
        int sum = pv;
        #pragma unroll
        for (int off = 1; off < 64; off <<= 1) {
            int x = __shfl_up(sum, off, 64);
            if (t >= off) sum += x;
        }
        pos64[t] = sum - pv;
        if (t == 63) s_ptot = sum;
    }
    __syncthreads();
    int ptot = s_ptot;

    // zero padded region, then scatter real records into padded positions
    for (int i = t; i < ptot; i += 256) sout[i] = make_int2(0, 0);
    __syncthreads();

    for (int i = t; i < cnt; i += 256) {
        int2 p = sin[i];
        int l = (p.x >> 18) & 63;
        int dst = atomicAdd(&pos64[l], 1);
        sout[dst] = make_int2(p.x & 0x3FFFF, p.y);
    }
    __syncthreads();

    for (int i = t; i < ptot; i += 256)
        rec[(size_t)b * STR + i] = sout[i];

    if (t < 64) {
        int v = cnt64[t];
        int pv = (v + PADM - 1) & ~(PADM - 1);
        int sum = pv;
        #pragma unroll
        for (int off = 1; off < 64; off <<= 1) {
            int x = __shfl_up(sum, off, 64);
            if (t >= off) sum += x;
        }
        int start = b * STR + (sum - pv);
        int node = b * 64 + t;
        if (node < N_NODES) range[node] = make_int2(start, start + pv);
    }
}

// ---------------------------------------------------------------------------
// side_k: wave-per-node segment-sum over bf16 rows (R4/R7-verified 63.3us
// form — the measured rate limit for the random 128B table gather; R5 proved
// MLP isn't the bottleneck, R6 proved nontemporal hints hurt).
// ---------------------------------------------------------------------------
template<int DIN>
__global__ __launch_bounds__(256)
void side_k(const int2* __restrict__ range, const int2* __restrict__ rec,
            const unsigned short* __restrict__ tab, float* __restrict__ side) {
    constexpr int LPR = DIN / 8;       // 8 (D64), 4 (D32)
    constexpr int EPW = 64 / LPR;      // 8 (D64), 16 (D32)

    int w = threadIdx.x >> 6;
    int lane = threadIdx.x & 63;
    int h = blockIdx.x * 4 + w;

    int2 rg = range[h];
    int e0 = rg.x, e1 = rg.y;          // e1 - e0 is a multiple of 16
    int g = lane / LPR;
    int q = lane % LPR;

    float acc[8];
    #pragma unroll
    for (int j = 0; j < 8; ++j) acc[j] = 0.f;

    int e = e0;
    for (; e + 2 * EPW <= e1; e += 2 * EPW) {
        int2 p0 = rec[e + g];
        int2 p1 = rec[e + EPW + g];
        float a0 = __int_as_float(p0.y);
        float a1 = __int_as_float(p1.y);
        uint4 d0 = *(const uint4*)(tab + (unsigned)(p0.x * DIN) + q * 8);
        uint4 d1 = *(const uint4*)(tab + (unsigned)(p1.x * DIN) + q * 8);
        acc[0] = fmaf(a0, bf_lo(d0.x), acc[0]);
        acc[1] = fmaf(a0, bf_hi(d0.x), acc[1]);
        acc[2] = fmaf(a0, bf_lo(d0.y), acc[2]);
        acc[3] = fmaf(a0, bf_hi(d0.y), acc[3]);
        acc[4] = fmaf(a0, bf_lo(d0.z), acc[4]);
        acc[5] = fmaf(a0, bf_hi(d0.z), acc[5]);
        acc[6] = fmaf(a0, bf_lo(d0.w), acc[6]);
        acc[7] = fmaf(a0, bf_hi(d0.w), acc[7]);
        acc[0] = fmaf(a1, bf_lo(d1.x), acc[0]);
        acc[1] = fmaf(a1, bf_hi(d1.x), acc[1]);
        acc[2] = fmaf(a1, bf_lo(d1.y), acc[2]);
        acc[3] = fmaf(a1, bf_hi(d1.y), acc[3]);
        acc[4] = fmaf(a1, bf_lo(d1.z), acc[4]);
        acc[5] = fmaf(a1, bf_hi(d1.z), acc[5]);
        acc[6] = fmaf(a1, bf_lo(d1.w), acc[6]);
        acc[7] = fmaf(a1, bf_hi(d1.w), acc[7]);
    }
    if (e < e1) {                      // remainder is exactly EPW (D32 only)
        int2 p0 = rec[e + g];
        float a0 = __int_as_float(p0.y);
        uint4 d0 = *(const uint4*)(tab + (unsigned)(p0.x * DIN) + q * 8);
        acc[0] = fmaf(a0, bf_lo(d0.x), acc[0]);
        acc[1] = fmaf(a0, bf_hi(d0.x), acc[1]);
        acc[2] = fmaf(a0, bf_lo(d0.y), acc[2]);
        acc[3] = fmaf(a0, bf_hi(d0.y), acc[3]);
        acc[4] = fmaf(a0, bf_lo(d0.z), acc[4]);
        acc[5] = fmaf(a0, bf_hi(d0.z), acc[5]);
        acc[6] = fmaf(a0, bf_lo(d0.w), acc[6]);
        acc[7] = fmaf(a0, bf_hi(d0.w), acc[7]);
    }

    #pragma unroll
    for (int off = LPR; off < 64; off <<= 1)
        #pragma unroll
        for (int j = 0; j < 8; ++j) acc[j] += __shfl_xor(acc[j], off, 64);

    if (lane < LPR) {
        float* dst = side + (size_t)h * DIN + q * 8;
        *(float4*)dst       = make_float4(acc[0], acc[1], acc[2], acc[3]);
        *(float4*)(dst + 4) = make_float4(acc[4], acc[5], acc[6], acc[7]);
    }
}

// ---------------------------------------------------------------------------
// transform_k: tiled vector GEMM. ego_in is bf16 (or fp32 user/ent when
// CONCAT). Output bf16 (OUT_BF) or fp32.  (R2-verified structure.)
// ---------------------------------------------------------------------------
template<int DIN, int DOUT, int TILE_ROWS, bool CONCAT, bool OUT_BF>
__global__ __launch_bounds__(256)
void transform_k(const unsigned short* __restrict__ ego_in,
                 const float* __restrict__ user_emb, const float* __restrict__ ent_emb,
                 const float* __restrict__ side,
                 const float* __restrict__ Wgc, const float* __restrict__ bgc,
                 const float* __restrict__ Wbi, const float* __restrict__ bbi,
                 void* __restrict__ ego_out) {
    constexpr int NG = DOUT / 8;
    constexpr int RG = 256 / NG;
    constexpr int RT = TILE_ROWS / RG;
    constexpr int STRIDE = DIN + 4;
    constexpr int KC8 = DIN / 8;

    __shared__ float sWgc[DIN * DOUT], sWbi[DIN * DOUT];
    __shared__ float sU[TILE_ROWS * STRIDE], sV[TILE_ROWS * STRIDE];

    int t = threadIdx.x;

    for (int i = t * 4; i < DIN * DOUT; i += 1024) {
        *(float4*)&sWgc[i] = *(const float4*)&Wgc[i];
        *(float4*)&sWbi[i] = *(const float4*)&Wbi[i];
    }

    int base = blockIdx.x * TILE_ROWS;
    for (int f = t; f < TILE_ROWS * KC8; f += 256) {
        int row = f / KC8, c8 = f % KC8;
        int n = base + row;
        int nc = n < N_NODES ? n : N_NODES - 1;
        float ev[8];
        if (CONCAT) {
            const float* erow = (nc < N_USERS) ? user_emb + (size_t)nc * 64
                                               : ent_emb + (size_t)(nc - N_USERS) * 64;
            float4 a = *(const float4*)(erow + c8 * 8);
            float4 b = *(const float4*)(erow + c8 * 8 + 4);
            ev[0] = a.x; ev[1] = a.y; ev[2] = a.z; ev[3] = a.w;
            ev[4] = b.x; ev[5] = b.y; ev[6] = b.z; ev[7] = b.w;
        } else {
            uint4 d = *(const uint4*)(ego_in + (size_t)nc * DIN + c8 * 8);
            ev[0] = bf_lo(d.x); ev[1] = bf_hi(d.x);
            ev[2] = bf_lo(d.y); ev[3] = bf_hi(d.y);
            ev[4] = bf_lo(d.z); ev[5] = bf_hi(d.z);
            ev[6] = bf_lo(d.w); ev[7] = bf_hi(d.w);
        }
        const float* srow = side + (size_t)nc * DIN + c8 * 8;
        float4 s0 = *(const float4*)srow;
        float4 s1 = *(const float4*)(srow + 4);
        float sv8[8] = {s0.x, s0.y, s0.z, s0.w, s1.x, s1.y, s1.z, s1.w};
        float* pu = &sU[row * STRIDE + c8 * 8];
        float* pv = &sV[row * STRIDE + c8 * 8];
        *(float4*)pu       = make_float4(ev[0] + sv8[0], ev[1] + sv8[1], ev[2] + sv8[2], ev[3] + sv8[3]);
        *(float4*)(pu + 4) = make_float4(ev[4] + sv8[4], ev[5] + sv8[5], ev[6] + sv8[6], ev[7] + sv8[7]);
        *(float4*)pv       = make_float4(ev[0] * sv8[0], ev[1] * sv8[1], ev[2] * sv8[2], ev[3] * sv8[3]);
        *(float4*)(pv + 4) = make_float4(ev[4] * sv8[4], ev[5] * sv8[5], ev[6] * sv8[6], ev[7] * sv8[7]);
    }
    __syncthreads();

    int cg = t % NG, rgi = t / NG;
    int c0 = cg * 8;
    int r0 = rgi * RT;

    float accg[RT][8], accb[RT][8];
    #pragma unroll
    for (int r = 0; r < RT; ++r)
        #pragma unroll
        for (int j = 0; j < 8; ++j) { accg[r][j] = 0.f; accb[r][j] = 0.f; }

    for (int k = 0; k < DIN; k += 4) {
        float4 u4[RT], v4[RT];
        #pragma unroll
        for (int r = 0; r < RT; ++r) {
            u4[r] = *(const float4*)&sU[(r0 + r) * STRIDE + k];
            v4[r] = *(const float4*)&sV[(r0 + r) * STRIDE + k];
        }
        #pragma unroll
        for (int kk = 0; kk < 4; ++kk) {
            float4 wg0 = *(const float4*)&sWgc[(k + kk) * DOUT + c0];
            float4 wg1 = *(const float4*)&sWgc[(k + kk) * DOUT + c0 + 4];
            float4 wb0 = *(const float4*)&sWbi[(k + kk) * DOUT + c0];
            float4 wb1 = *(const float4*)&sWbi[(k + kk) * DOUT + c0 + 4];
            #pragma unroll
            for (int r = 0; r < RT; ++r) {
                float u = ((const float*)&u4[r])[kk];
                float v = ((const float*)&v4[r])[kk];
                accg[r][0] = fmaf(u, wg0.x, accg[r][0]);
                accg[r][1] = fmaf(u, wg0.y, accg[r][1]);
                accg[r][2] = fmaf(u, wg0.z, accg[r][2]);
                accg[r][3] = fmaf(u, wg0.w, accg[r][3]);
                accg[r][4] = fmaf(u, wg1.x, accg[r][4]);
                accg[r][5] = fmaf(u, wg1.y, accg[r][5]);
                accg[r][6] = fmaf(u, wg1.z, accg[r][6]);
                accg[r][7] = fmaf(u, wg1.w, accg[r][7]);
                accb[r][0] = fmaf(v, wb0.x, accb[r][0]);
                accb[r][1] = fmaf(v, wb0.y, accb[r][1]);
                accb[r][2] = fmaf(v, wb0.z, accb[r][2]);
                accb[r][3] = fmaf(v, wb0.w, accb[r][3]);
                accb[r][4] = fmaf(v, wb1.x, accb[r][4]);
                accb[r][5] = fmaf(v, wb1.y, accb[r][5]);
                accb[r][6] = fmaf(v, wb1.z, accb[r][6]);
                accb[r][7] = fmaf(v, wb1.w, accb[r][7]);
            }
        }
    }

    float4 bg0 = *(const float4*)&bgc[c0];
    float4 bg1 = *(const float4*)&bgc[c0 + 4];
    float4 bb0 = *(const float4*)&bbi[c0];
    float4 bb1 = *(const float4*)&bbi[c0 + 4];
    float bg[8] = {bg0.x, bg0.y, bg0.z, bg0.w, bg1.x, bg1.y, bg1.z, bg1.w};
    float bb[8] = {bb0.x, bb0.y, bb0.z, bb0.w, bb1.x, bb1.y, bb1.z, bb1.w};

    #pragma unroll
    for (int r = 0; r < RT; ++r) {
        int n = base + r0 + r;
        if (n < N_NODES) {
            float o[8];
            #pragma unroll
            for (int j = 0; j < 8; ++j) {
                float gg = accg[r][j] + bg[j];
                float b2 = accb[r][j] + bb[j];
                gg = gg > 0.f ? gg : SLOPE * gg;
                b2 = b2 > 0.f ? b2 : SLOPE * b2;
                o[j] = gg + b2;
            }
            if (OUT_BF) {
                unsigned short* dst = (unsigned short*)ego_out + (size_t)n * DOUT + c0;
                uint4 wv;
                wv.x = f2bf(o[0]) | (f2bf(o[1]) << 16);
                wv.y = f2bf(o[2]) | (f2bf(o[3]) << 16);
                wv.z = f2bf(o[4]) | (f2bf(o[5]) << 16);
                wv.w = f2bf(o[6]) | (f2bf(o[7]) << 16);
                *(uint4*)dst = wv;
            } else {
                float* dst = (float*)ego_out + (size_t)n * DOUT + c0;
                *(float4*)dst       = make_float4(o[0], o[1], o[2], o[3]);
                *(float4*)(dst + 4) = make_float4(o[4], o[5], o[6], o[7]);
            }
        }
    }
}

// ---------------------------------------------------------------------------
// Gather: out rows = [ego0(64) | norm(ego1)(64) | norm(ego2)(32) | norm(ego3)(16)]
// 256-thread blocks, 4 rows/block (one wave each; shuffles are per-wave).
// ---------------------------------------------------------------------------
__global__ __launch_bounds__(256)
void gather_k(const int* __restrict__ users, const int* __restrict__ pos,
              const int* __restrict__ neg,
              const float* __restrict__ user_emb, const float* __restrict__ ent_emb,
              const unsigned short* __restrict__ ego1_bf,
              const unsigned short* __restrict__ ego2_bf,
              const float* __restrict__ ego3,
              float* __restrict__ out) {
    int w = threadIdx.x >> 6;
    int lane = threadIdx.x & 63;
    int r = blockIdx.x * 4 + w;
    int which = r / BATCH;
    int i = r - which * BATCH;
    int node;
    if (which == 0)      node = users[i];
    else if (which == 1) node = N_USERS + pos[i];
    else                 node = N_USERS + neg[i];

    float* o = out + (size_t)r * 176;

    float x0 = (node < N_USERS) ? user_emb[(size_t)node * 64 + lane]
                                : ent_emb[(size_t)(node - N_USERS) * 64 + lane];
    o[lane] = x0;

    float x1 = __uint_as_float((unsigned)ego1_bf[(size_t)node * 64 + lane] << 16);
    float ss = x1 * x1;
    #pragma unroll
    for (int off = 32; off > 0; off >>= 1) ss += __shfl_xor(ss, off, 64);
    o[64 + lane] = x1 / fmaxf(sqrtf(ss), EPSF);

    float x2 = (lane < 32)
        ? __uint_as_float((unsigned)ego2_bf[(size_t)node * 32 + lane] << 16) : 0.f;
    float ss2 = x2 * x2;
    #pragma unroll
    for (int off = 32; off > 0; off >>= 1) ss2 += __shfl_xor(ss2, off, 64);
    if (lane < 32) o[128 + lane] = x2 / fmaxf(sqrtf(ss2), EPSF);

    float x3 = (lane < 16) ? ego3[(size_t)node * 16 + lane] : 0.f;
    float ss3 = x3 * x3;
    #pragma unroll
    for (int off = 32; off > 0; off >>= 1) ss3 += __shfl_xor(ss3, off, 64);
    if (lane < 16) o[160 + lane] = x3 / fmaxf(sqrtf(ss3), EPSF);
}

// ---------------------------------------------------------------------------
extern "C" void kernel_launch(void* const* d_in, const int* in_sizes, int n_in,
                              void* d_out, int out_size, void* d_ws, size_t ws_size,
                              hipStream_t stream) {
    const int*   users    = (const int*)d_in[0];
    const int*   pos      = (const int*)d_in[1];
    const int*   neg      = (const int*)d_in[2];
    const int*   all_h    = (const int*)d_in[3];
    const int*   all_t    = (const int*)d_in[4];
    const float* A        = (const float*)d_in[5];
    const float* user_emb = (const float*)d_in[6];
    const float* ent_emb  = (const float*)d_in[7];
    const float* Wgc0 = (const float*)d_in[8];
    const float* bgc0 = (const float*)d_in[9];
    const float* Wbi0 = (const float*)d_in[10];
    const float* bbi0 = (const float*)d_in[11];
    const float* Wgc1 = (const float*)d_in[12];
    const float* bgc1 = (const float*)d_in[13];
    const float* Wbi1 = (const float*)d_in[14];
    const float* bbi1 = (const float*)d_in[15];
    const float* Wgc2 = (const float*)d_in[16];
    const float* bgc2 = (const float*)d_in[17];
    const float* Wbi2 = (const float*)d_in[18];
    const float* bbi2 = (const float*)d_in[19];

    // ---- workspace (256B-aligned).
    // rec_src (24MB) aliases the front of side (37.5MB): rec_src dead after
    // local_sort, side first written by side_k (after). rec (dest) dead after
    // side L2 -> ego3 aliases it.
    char* p = (char*)d_ws;
    int*   prefix  = (int*)p;            p += ((size_t)NPB * PFW * 4 + 255) & ~255ull;
    float* side    = (float*)p;
    int2*  rec_src = (int2*)p;           p += ((size_t)N_NODES * 64 * 4 + 255) & ~255ull;
    int2*  rec     = (int2*)p;           char* rec_base = p;
    p += ((size_t)NBUK * STR * 8 + 255) & ~255ull;
    int2*  range   = (int2*)p;           p += ((size_t)N_NODES * 8 + 255) & ~255ull;
    unsigned short* ego0_bf = (unsigned short*)p; p += ((size_t)N_NODES * 64 * 2 + 255) & ~255ull;
    unsigned short* ego1_bf = (unsigned short*)p; p += ((size_t)N_NODES * 64 * 2 + 255) & ~255ull;
    unsigned short* ego2_bf = (unsigned short*)p; p += ((size_t)N_NODES * 32 * 2 + 255) & ~255ull;
    float* ego3    = (float*)rec_base;   // aliases rec (dead by then)
    float* out     = (float*)d_out;

    const int nodeBlocks = N_NODES / 4;

    // ---- prep: merged {block-local partition + bf16 cast} + bucket assembly
    prep_k<<<NPB + CASTB, PBLK, 0, stream>>>(all_h, all_t, A, prefix, rec_src,
                                             user_emb, ent_emb, ego0_bf);
    local_sort_k<<<NBUK, 256, 0, stream>>>(prefix, rec_src, rec, range);

    // ---- layer 0: 64 -> 64 ----
    side_k<64><<<nodeBlocks, 256, 0, stream>>>(range, rec, ego0_bf, side);
    transform_k<64, 64, 64, true, true><<<(N_NODES + 63) / 64, 256, 0, stream>>>(
        nullptr, user_emb, ent_emb, side, Wgc0, bgc0, Wbi0, bbi0, ego1_bf);

    // ---- layer 1: 64 -> 32 ----
    side_k<64><<<nodeBlocks, 256, 0, stream>>>(range, rec, ego1_bf, side);
    transform_k<64, 32, 64, false, true><<<(N_NODES + 63) / 64, 256, 0, stream>>>(
        ego1_bf, nullptr, nullptr, side, Wgc1, bgc1, Wbi1, bbi1, ego2_bf);

    // ---- layer 2: 32 -> 16 ----
    side_k<32><<<nodeBlocks, 256, 0, stream>>>(range, rec, ego2_bf, side);
    transform_k<32, 16, 128, false, false><<<(N_NODES + 127) / 128, 256, 0, stream>>>(
        ego2_bf, nullptr, nullptr, side, Wgc2, bgc2, Wbi2, bbi2, ego3);

    // ---- final gather + lazy normalization ----
    gather_k<<<3 * BATCH / 4, 256, 0, stream>>>(
        users, pos, neg, user_emb, ent_emb, ego1_bf, ego2_bf, ego3, out);
}

// Round 9
// 441.426 us; speedup vs baseline: 1.1218x; 1.0798x over previous
//
#include <hip/hip_runtime.h>
#include <math.h>

#define N_USERS    50000
#define N_ENTITIES 100000
#define N_NODES    150000
#define N_EDGES    3000000
#define BATCH      8192
#define SLOPE      0.2f
#define EPSF       1e-12f

// bucket partition: bucket = h>>6 (64 nodes per bucket)
#define NBUK   2344            // ceil(150000/64)
#define CAP    1536            // per-bucket real-record capacity (mean 1280, +7.1 sd)
#define STR    2560            // physical bucket stride: CAP + 64*16 padding worst case
#define PADM   16              // per-node segment padded to multiple of 16 edges
#define BLK_E  12288           // edges per partition block (12 per thread)
#define NPB    ((N_EDGES + BLK_E - 1) / BLK_E)   // 245
#define PBLK   1024            // partition block size (16 waves)
#define EPT    (BLK_E / PBLK)  // 12 edges per thread
#define CH     4096            // copy-out chunk (positions per LDS flush)
#define PFW    (NBUK + 1)      // prefix row width (per-block exclusive starts + total)
#define CASTB  ((N_NODES * 64 / 4 + PBLK - 1) / PBLK)   // 2344 cast blocks

__device__ __forceinline__ unsigned f2bf(float f) {       // RNE fp32->bf16
    unsigned u = __float_as_uint(f);
    return (u + 0x7FFFu + ((u >> 16) & 1u)) >> 16;
}
__device__ __forceinline__ float bf_lo(unsigned d) { return __uint_as_float(d << 16); }
// hi bf16 WITHOUT masking low bits: garbage adds <=2^-16 relative error,
// strictly dominated by the 2^-9 bf16 rounding already present.
__device__ __forceinline__ float bf_hi(unsigned d) { return __uint_as_float(d); }

// ---------------------------------------------------------------------------
// prep_k: merged {partition -> block-contiguous staged records} + bf16 cast.
// (R8-verified: block-contiguous rec_src + prefix rows; no global atomics,
// no RMW, no memset.) Cast body (blocks >= NPB) unchanged.
// ---------------------------------------------------------------------------
__global__ __launch_bounds__(PBLK)
void prep_k(const int* __restrict__ all_h, const int* __restrict__ all_t,
            const float* __restrict__ A,
            int* __restrict__ prefix, int2* __restrict__ rec_src,
            const float* __restrict__ user_emb, const float* __restrict__ ent_emb,
            unsigned short* __restrict__ ego0_bf) {
    __shared__ int pos[NBUK];      // counts -> excl starts -> cursors
    __shared__ int wsum[PBLK / 64];
    __shared__ int2 srec[CH];      // staged records for current chunk

    int t = threadIdx.x;

    if (blockIdx.x >= NPB) {
        // ---- cast body: concat(user,ent) -> bf16 table ----
        int idx = (blockIdx.x - NPB) * PBLK + t;
        const int total = N_NODES * 64 / 4;
        if (idx >= total) return;
        int ge = idx * 4;
        const float* src = (ge < N_USERS * 64) ? user_emb + ge
                                               : ent_emb + (ge - N_USERS * 64);
        float4 v = *(const float4*)src;
        ushort4 o;
        o.x = (unsigned short)f2bf(v.x);
        o.y = (unsigned short)f2bf(v.y);
        o.z = (unsigned short)f2bf(v.z);
        o.w = (unsigned short)f2bf(v.w);
        *(ushort4*)(ego0_bf + ge) = o;
        return;
    }

    // ---- partition body ----
    for (int i = t; i < NBUK; i += PBLK) pos[i] = 0;
    __syncthreads();

    int e0 = blockIdx.x * BLK_E;
    int e1 = e0 + BLK_E; if (e1 > N_EDGES) e1 = N_EDGES;
    int tot = e1 - e0;

    // single coalesced read of all three edge streams into registers
    int h[EPT]; int tt[EPT]; float aa[EPT];
    #pragma unroll
    for (int k = 0; k < EPT; ++k) {
        int e = e0 + k * PBLK + t;
        bool v = e < e1;
        h[k]  = v ? all_h[e] : -1;
        tt[k] = v ? all_t[e] : 0;
        aa[k] = v ? A[e] : 0.f;
    }
    #pragma unroll
    for (int k = 0; k < EPT; ++k)
        if (h[k] >= 0) atomicAdd(&pos[h[k] >> 6], 1);
    __syncthreads();

    // sweep 1: read own bucket counts
    int c[3];
    int i0 = t * 3;
    int tsum = 0;
    #pragma unroll
    for (int j = 0; j < 3; ++j) {
        int idx = i0 + j;
        c[j] = (idx < NBUK) ? pos[idx] : 0;
        tsum += c[j];
    }

    // block-wide exclusive scan of per-thread sums (16 waves of 64)
    int lane = t & 63, w = t >> 6;
    int incl = tsum;
    #pragma unroll
    for (int off = 1; off < 64; off <<= 1) {
        int x = __shfl_up(incl, off, 64);
        if (lane >= off) incl += x;
    }
    if (lane == 63) wsum[w] = incl;
    __syncthreads();   // also fences all sweep-1 pos[] reads before overwrite
    int wbase = 0;
    for (int j = 0; j < w; ++j) wbase += wsum[j];
    int excl = wbase + (incl - tsum);

    // sweep 2: exclusive starts into pos AND into this block's prefix row
    size_t prow = (size_t)blockIdx.x * PFW;
    #pragma unroll
    for (int j = 0; j < 3; ++j) {
        int idx = i0 + j;
        if (idx < NBUK) { pos[idx] = excl; prefix[prow + idx] = excl; }
        excl += c[j];
    }
    if (t == PBLK - 1) prefix[prow + NBUK] = excl;   // == tot (total real count)
    __syncthreads();

    // placement: block-sorted position per edge (permutation of [0,tot))
    int pp[EPT];
    #pragma unroll
    for (int k = 0; k < EPT; ++k)
        pp[k] = (h[k] >= 0) ? atomicAdd(&pos[h[k] >> 6], 1) : -1;

    // chunked reg->LDS scatter + LINEAR block-contiguous flush (16B stores)
    for (int base = 0; base < tot; base += CH) {
        __syncthreads();                       // LDS chunk free (prev flush done)
        int lim = tot - base; if (lim > CH) lim = CH;
        #pragma unroll
        for (int k = 0; k < EPT; ++k) {
            int s = pp[k] - base;
            if (s >= 0 && s < CH)
                srec[s] = make_int2(tt[k] | ((h[k] & 63) << 18), __float_as_int(aa[k]));
        }
        __syncthreads();
        // every slot [0,lim) is filled (pp is a permutation); lim is even
        const int4* s4 = (const int4*)srec;
        int4* d4 = (int4*)(rec_src + e0 + base);
        int lim2 = lim >> 1;
        for (int s = t; s < lim2; s += PBLK) d4[s] = s4[s];
    }
}

// ---------------------------------------------------------------------------
// local_sort_k: assemble bucket b from the 245 block-local runs (thread t
// owns run t via prefix[t][b..b+1]; 256-wide scan gives LDS destinations),
// then 64-bin counting sort with pad-16 zero records {t=0,a=0}. (R8-verified)
// ---------------------------------------------------------------------------
__global__ __launch_bounds__(256)
void local_sort_k(const int* __restrict__ prefix, const int2* __restrict__ rec_src,
                  int2* __restrict__ rec, int2* __restrict__ range) {
    __shared__ int2 sin[CAP];
    __shared__ int2 sout[STR];
    __shared__ int cnt64[64];
    __shared__ int pos64[64];
    __shared__ int sc[256];
    __shared__ int s_ptot;
    int b = blockIdx.x, t = threadIdx.x;

    if (t < 64) cnt64[t] = 0;

    // run t = this bucket's records inside prep block t's chunk
    int rstart = 0, n_t = 0;
    if (t < NPB) {
        const int* prow = prefix + (size_t)t * PFW + b;
        int s0 = prow[0];
        int s1 = prow[1];
        rstart = t * BLK_E + s0;
        n_t = s1 - s0;
    }
    sc[t] = n_t;
    __syncthreads();

    // 256-wide inclusive scan (Hillis-Steele, double barrier)
    for (int off = 1; off < 256; off <<= 1) {
        int v = sc[t];
        int u = (t >= off) ? sc[t - off] : 0;
        __syncthreads();
        sc[t] = v + u;
        __syncthreads();
    }
    int cnt = sc[255]; if (cnt > CAP) cnt = CAP;

    // gather this thread's run into sin + histogram by h&63
    if (t < NPB && n_t > 0) {
        int d = sc[t] - n_t;
        for (int j = 0; j < n_t; ++j) {
            int dj = d + j;
            if (dj >= CAP) break;
            int2 p = rec_src[rstart + j];
            sin[dj] = p;
            atomicAdd(&cnt64[(p.x >> 18) & 63], 1);
        }
    }
    __syncthreads();

    if (t < 64) {
        int v = cnt64[t];
        int pv = (v + PADM - 1) & ~(PADM - 1);
        int sum = pv;
        #pragma unroll
        for (int off = 1; off < 64; off <<= 1) {
            int x = __shfl_up(sum, off, 64);
            if (t >= off) sum += x;
        }
        pos64[t] = sum - pv;
        if (t == 63) s_ptot = sum;
    }
    __syncthreads();
    int ptot = s_ptot;

    // zero padded region, then scatter real records into padded positions
    for (int i = t; i < ptot; i += 256) sout[i] = make_int2(0, 0);
    __syncthreads();

    for (int i = t; i < cnt; i += 256) {
        int2 p = sin[i];
        int l = (p.x >> 18) & 63;
        int dst = atomicAdd(&pos64[l], 1);
        sout[dst] = make_int2(p.x & 0x3FFFF, p.y);
    }
    __syncthreads();

    for (int i = t; i < ptot; i += 256)
        rec[(size_t)b * STR + i] = sout[i];

    if (t < 64) {
        int v = cnt64[t];
        int pv = (v + PADM - 1) & ~(PADM - 1);
        int sum = pv;
        #pragma unroll
        for (int off = 1; off < 64; off <<= 1) {
            int x = __shfl_up(sum, off, 64);
            if (t >= off) sum += x;
        }
        int start = b * STR + (sum - pv);
        int node = b * 64 + t;
        if (node < N_NODES) range[node] = make_int2(start, start + pv);
    }
}

// ---------------------------------------------------------------------------
// side_k: wave-per-node segment-sum over bf16 rows (R4/R7/R8-verified 63.3us
// form — the measured rate limit for the random 128B table gather).
// Only instantiated for DIN=64 now; layer 2's side is computed lazily in
// final_k for sampled rows only (84% of side<32> was dead work).
// ---------------------------------------------------------------------------
template<int DIN>
__global__ __launch_bounds__(256)
void side_k(const int2* __restrict__ range, const int2* __restrict__ rec,
            const unsigned short* __restrict__ tab, float* __restrict__ side) {
    constexpr int LPR = DIN / 8;       // 8 (D64)
    constexpr int EPW = 64 / LPR;      // 8 (D64)

    int w = threadIdx.x >> 6;
    int lane = threadIdx.x & 63;
    int h = blockIdx.x * 4 + w;

    int2 rg = range[h];
    int e0 = rg.x, e1 = rg.y;          // e1 - e0 is a multiple of 16
    int g = lane / LPR;
    int q = lane % LPR;

    float acc[8];
    #pragma unroll
    for (int j = 0; j < 8; ++j) acc[j] = 0.f;

    int e = e0;
    for (; e + 2 * EPW <= e1; e += 2 * EPW) {
        int2 p0 = rec[e + g];
        int2 p1 = rec[e + EPW + g];
        float a0 = __int_as_float(p0.y);
        float a1 = __int_as_float(p1.y);
        uint4 d0 = *(const uint4*)(tab + (unsigned)(p0.x * DIN) + q * 8);
        uint4 d1 = *(const uint4*)(tab + (unsigned)(p1.x * DIN) + q * 8);
        acc[0] = fmaf(a0, bf_lo(d0.x), acc[0]);
        acc[1] = fmaf(a0, bf_hi(d0.x), acc[1]);
        acc[2] = fmaf(a0, bf_lo(d0.y), acc[2]);
        acc[3] = fmaf(a0, bf_hi(d0.y), acc[3]);
        acc[4] = fmaf(a0, bf_lo(d0.z), acc[4]);
        acc[5] = fmaf(a0, bf_hi(d0.z), acc[5]);
        acc[6] = fmaf(a0, bf_lo(d0.w), acc[6]);
        acc[7] = fmaf(a0, bf_hi(d0.w), acc[7]);
        acc[0] = fmaf(a1, bf_lo(d1.x), acc[0]);
        acc[1] = fmaf(a1, bf_hi(d1.x), acc[1]);
        acc[2] = fmaf(a1, bf_lo(d1.y), acc[2]);
        acc[3] = fmaf(a1, bf_hi(d1.y), acc[3]);
        acc[4] = fmaf(a1, bf_lo(d1.z), acc[4]);
        acc[5] = fmaf(a1, bf_hi(d1.z), acc[5]);
        acc[6] = fmaf(a1, bf_lo(d1.w), acc[6]);
        acc[7] = fmaf(a1, bf_hi(d1.w), acc[7]);
    }
    if (e < e1) {                      // remainder is exactly EPW
        int2 p0 = rec[e + g];
        float a0 = __int_as_float(p0.y);
        uint4 d0 = *(const uint4*)(tab + (unsigned)(p0.x * DIN) + q * 8);
        acc[0] = fmaf(a0, bf_lo(d0.x), acc[0]);
        acc[1] = fmaf(a0, bf_hi(d0.x), acc[1]);
        acc[2] = fmaf(a0, bf_lo(d0.y), acc[2]);
        acc[3] = fmaf(a0, bf_hi(d0.y), acc[3]);
        acc[4] = fmaf(a0, bf_lo(d0.z), acc[4]);
        acc[5] = fmaf(a0, bf_hi(d0.z), acc[5]);
        acc[6] = fmaf(a0, bf_lo(d0.w), acc[6]);
        acc[7] = fmaf(a0, bf_hi(d0.w), acc[7]);
    }

    #pragma unroll
    for (int off = LPR; off < 64; off <<= 1)
        #pragma unroll
        for (int j = 0; j < 8; ++j) acc[j] += __shfl_xor(acc[j], off, 64);

    if (lane < LPR) {
        float* dst = side + (size_t)h * DIN + q * 8;
        *(float4*)dst       = make_float4(acc[0], acc[1], acc[2], acc[3]);
        *(float4*)(dst + 4) = make_float4(acc[4], acc[5], acc[6], acc[7]);
    }
}

// ---------------------------------------------------------------------------
// transform_k: tiled vector GEMM. ego_in is bf16 (or fp32 user/ent when
// CONCAT). Output bf16. (R2-verified structure; only layers 0 and 1 now.)
// ---------------------------------------------------------------------------
template<int DIN, int DOUT, int TILE_ROWS, bool CONCAT>
__global__ __launch_bounds__(256)
void transform_k(const unsigned short* __restrict__ ego_in,
                 const float* __restrict__ user_emb, const float* __restrict__ ent_emb,
                 const float* __restrict__ side,
                 const float* __restrict__ Wgc, const float* __restrict__ bgc,
                 const float* __restrict__ Wbi, const float* __restrict__ bbi,
                 unsigned short* __restrict__ ego_out) {
    constexpr int NG = DOUT / 8;
    constexpr int RG = 256 / NG;
    constexpr int RT = TILE_ROWS / RG;
    constexpr int STRIDE = DIN + 4;
    constexpr int KC8 = DIN / 8;

    __shared__ float sWgc[DIN * DOUT], sWbi[DIN * DOUT];
    __shared__ float sU[TILE_ROWS * STRIDE], sV[TILE_ROWS * STRIDE];

    int t = threadIdx.x;

    for (int i = t * 4; i < DIN * DOUT; i += 1024) {
        *(float4*)&sWgc[i] = *(const float4*)&Wgc[i];
        *(float4*)&sWbi[i] = *(const float4*)&Wbi[i];
    }

    int base = blockIdx.x * TILE_ROWS;
    for (int f = t; f < TILE_ROWS * KC8; f += 256) {
        int row = f / KC8, c8 = f % KC8;
        int n = base + row;
        int nc = n < N_NODES ? n : N_NODES - 1;
        float ev[8];
        if (CONCAT) {
            const float* erow = (nc < N_USERS) ? user_emb + (size_t)nc * 64
                                               : ent_emb + (size_t)(nc - N_USERS) * 64;
            float4 a = *(const float4*)(erow + c8 * 8);
            float4 b = *(const float4*)(erow + c8 * 8 + 4);
            ev[0] = a.x; ev[1] = a.y; ev[2] = a.z; ev[3] = a.w;
            ev[4] = b.x; ev[5] = b.y; ev[6] = b.z; ev[7] = b.w;
        } else {
            uint4 d = *(const uint4*)(ego_in + (size_t)nc * DIN + c8 * 8);
            ev[0] = bf_lo(d.x); ev[1] = bf_hi(d.x);
            ev[2] = bf_lo(d.y); ev[3] = bf_hi(d.y);
            ev[4] = bf_lo(d.z); ev[5] = bf_hi(d.z);
            ev[6] = bf_lo(d.w); ev[7] = bf_hi(d.w);
        }
        const float* srow = side + (size_t)nc * DIN + c8 * 8;
        float4 s0 = *(const float4*)srow;
        float4 s1 = *(const float4*)(srow + 4);
        float sv8[8] = {s0.x, s0.y, s0.z, s0.w, s1.x, s1.y, s1.z, s1.w};
        float* pu = &sU[row * STRIDE + c8 * 8];
        float* pv = &sV[row * STRIDE + c8 * 8];
        *(float4*)pu       = make_float4(ev[0] + sv8[0], ev[1] + sv8[1], ev[2] + sv8[2], ev[3] + sv8[3]);
        *(float4*)(pu + 4) = make_float4(ev[4] + sv8[4], ev[5] + sv8[5], ev[6] + sv8[6], ev[7] + sv8[7]);
        *(float4*)pv       = make_float4(ev[0] * sv8[0], ev[1] * sv8[1], ev[2] * sv8[2], ev[3] * sv8[3]);
        *(float4*)(pv + 4) = make_float4(ev[4] * sv8[4], ev[5] * sv8[5], ev[6] * sv8[6], ev[7] * sv8[7]);
    }
    __syncthreads();

    int cg = t % NG, rgi = t / NG;
    int c0 = cg * 8;
    int r0 = rgi * RT;

    float accg[RT][8], accb[RT][8];
    #pragma unroll
    for (int r = 0; r < RT; ++r)
        #pragma unroll
        for (int j = 0; j < 8; ++j) { accg[r][j] = 0.f; accb[r][j] = 0.f; }

    for (int k = 0; k < DIN; k += 4) {
        float4 u4[RT], v4[RT];
        #pragma unroll
        for (int r = 0; r < RT; ++r) {
            u4[r] = *(const float4*)&sU[(r0 + r) * STRIDE + k];
            v4[r] = *(const float4*)&sV[(r0 + r) * STRIDE + k];
        }
        #pragma unroll
        for (int kk = 0; kk < 4; ++kk) {
            float4 wg0 = *(const float4*)&sWgc[(k + kk) * DOUT + c0];
            float4 wg1 = *(const float4*)&sWgc[(k + kk) * DOUT + c0 + 4];
            float4 wb0 = *(const float4*)&sWbi[(k + kk) * DOUT + c0];
            float4 wb1 = *(const float4*)&sWbi[(k + kk) * DOUT + c0 + 4];
            #pragma unroll
            for (int r = 0; r < RT; ++r) {
                float u = ((const float*)&u4[r])[kk];
                float v = ((const float*)&v4[r])[kk];
                accg[r][0] = fmaf(u, wg0.x, accg[r][0]);
                accg[r][1] = fmaf(u, wg0.y, accg[r][1]);
                accg[r][2] = fmaf(u, wg0.z, accg[r][2]);
                accg[r][3] = fmaf(u, wg0.w, accg[r][3]);
                accg[r][4] = fmaf(u, wg1.x, accg[r][4]);
                accg[r][5] = fmaf(u, wg1.y, accg[r][5]);
                accg[r][6] = fmaf(u, wg1.z, accg[r][6]);
                accg[r][7] = fmaf(u, wg1.w, accg[r][7]);
                accb[r][0] = fmaf(v, wb0.x, accb[r][0]);
                accb[r][1] = fmaf(v, wb0.y, accb[r][1]);
                accb[r][2] = fmaf(v, wb0.z, accb[r][2]);
                accb[r][3] = fmaf(v, wb0.w, accb[r][3]);
                accb[r][4] = fmaf(v, wb1.x, accb[r][4]);
                accb[r][5] = fmaf(v, wb1.y, accb[r][5]);
                accb[r][6] = fmaf(v, wb1.z, accb[r][6]);
                accb[r][7] = fmaf(v, wb1.w, accb[r][7]);
            }
        }
    }

    float4 bg0 = *(const float4*)&bgc[c0];
    float4 bg1 = *(const float4*)&bgc[c0 + 4];
    float4 bb0 = *(const float4*)&bbi[c0];
    float4 bb1 = *(const float4*)&bbi[c0 + 4];
    float bg[8] = {bg0.x, bg0.y, bg0.z, bg0.w, bg1.x, bg1.y, bg1.z, bg1.w};
    float bb[8] = {bb0.x, bb0.y, bb0.z, bb0.w, bb1.x, bb1.y, bb1.z, bb1.w};

    #pragma unroll
    for (int r = 0; r < RT; ++r) {
        int n = base + r0 + r;
        if (n < N_NODES) {
            float o[8];
            #pragma unroll
            for (int j = 0; j < 8; ++j) {
                float gg = accg[r][j] + bg[j];
                float b2 = accb[r][j] + bb[j];
                gg = gg > 0.f ? gg : SLOPE * gg;
                b2 = b2 > 0.f ? b2 : SLOPE * b2;
                o[j] = gg + b2;
            }
            unsigned short* dst = ego_out + (size_t)n * DOUT + c0;
            uint4 wv;
            wv.x = f2bf(o[0]) | (f2bf(o[1]) << 16);
            wv.y = f2bf(o[2]) | (f2bf(o[3]) << 16);
            wv.z = f2bf(o[4]) | (f2bf(o[5]) << 16);
            wv.w = f2bf(o[6]) | (f2bf(o[7]) << 16);
            *(uint4*)dst = wv;
        }
    }
}

// ---------------------------------------------------------------------------
// final_k: per sampled row (wave per row): segments 0-2 as before, then
// LAZY layer-2: side2 computed in-register (exact side_k<32> body; pad-16
// ranges -> clamp-free), U/V redistributed via __shfl (no LDS, no barrier),
// 16-wide transform with transform_k's exact k-ascending FMA chain, bias +
// leaky, row norm, write. Replaces side_k<32> + transform_k L2 + gather_k:
// layer-2 work drops from 150000 nodes to 24576 sampled rows (~16%).
// ---------------------------------------------------------------------------
__global__ __launch_bounds__(256)
void final_k(const int* __restrict__ users, const int* __restrict__ pos,
             const int* __restrict__ neg,
             const float* __restrict__ user_emb, const float* __restrict__ ent_emb,
             const unsigned short* __restrict__ ego1_bf,
             const unsigned short* __restrict__ ego2_bf,
             const int2* __restrict__ range, const int2* __restrict__ rec,
             const float* __restrict__ Wgc, const float* __restrict__ bgc,
             const float* __restrict__ Wbi, const float* __restrict__ bbi,
             float* __restrict__ out) {
    __shared__ float sWgc[32 * 16], sWbi[32 * 16];
    int t = threadIdx.x;
    for (int i = t; i < 32 * 16; i += 256) { sWgc[i] = Wgc[i]; sWbi[i] = Wbi[i]; }
    __syncthreads();

    int w = t >> 6, lane = t & 63;
    int r = blockIdx.x * 4 + w;
    int which = r / BATCH;
    int i = r - which * BATCH;
    int node;
    if (which == 0)      node = users[i];
    else if (which == 1) node = N_USERS + pos[i];
    else                 node = N_USERS + neg[i];

    float* o = out + (size_t)r * 176;

    // segment 0: raw ego0
    float x0 = (node < N_USERS) ? user_emb[(size_t)node * 64 + lane]
                                : ent_emb[(size_t)(node - N_USERS) * 64 + lane];
    o[lane] = x0;

    // segment 1: norm ego1
    float x1 = __uint_as_float((unsigned)ego1_bf[(size_t)node * 64 + lane] << 16);
    float ss = x1 * x1;
    #pragma unroll
    for (int off = 32; off > 0; off >>= 1) ss += __shfl_xor(ss, off, 64);
    o[64 + lane] = x1 / fmaxf(sqrtf(ss), EPSF);

    // segment 2: norm ego2
    float x2 = (lane < 32)
        ? __uint_as_float((unsigned)ego2_bf[(size_t)node * 32 + lane] << 16) : 0.f;
    float ss2 = x2 * x2;
    #pragma unroll
    for (int off = 32; off > 0; off >>= 1) ss2 += __shfl_xor(ss2, off, 64);
    if (lane < 32) o[128 + lane] = x2 / fmaxf(sqrtf(ss2), EPSF);

    // ---- lazy layer 2: side2 (exact side_k<32> body, DIN=32) ----
    constexpr int LPR = 4, EPW = 16;
    int g = lane / LPR, q = lane % LPR;
    int2 rg = range[node];
    int e0 = rg.x, e1 = rg.y;          // multiple of 16

    float acc[8];
    #pragma unroll
    for (int j = 0; j < 8; ++j) acc[j] = 0.f;

    int e = e0;
    for (; e + 2 * EPW <= e1; e += 2 * EPW) {
        int2 p0 = rec[e + g];
        int2 p1 = rec[e + EPW + g];
        float a0 = __int_as_float(p0.y);
        float a1 = __int_as_float(p1.y);
        uint4 d0 = *(const uint4*)(ego2_bf + (unsigned)(p0.x * 32) + q * 8);
        uint4 d1 = *(const uint4*)(ego2_bf + (unsigned)(p1.x * 32) + q * 8);
        acc[0] = fmaf(a0, bf_lo(d0.x), acc[0]);
        acc[1] = fmaf(a0, bf_hi(d0.x), acc[1]);
        acc[2] = fmaf(a0, bf_lo(d0.y), acc[2]);
        acc[3] = fmaf(a0, bf_hi(d0.y), acc[3]);
        acc[4] = fmaf(a0, bf_lo(d0.z), acc[4]);
        acc[5] = fmaf(a0, bf_hi(d0.z), acc[5]);
        acc[6] = fmaf(a0, bf_lo(d0.w), acc[6]);
        acc[7] = fmaf(a0, bf_hi(d0.w), acc[7]);
        acc[0] = fmaf(a1, bf_lo(d1.x), acc[0]);
        acc[1] = fmaf(a1, bf_hi(d1.x), acc[1]);
        acc[2] = fmaf(a1, bf_lo(d1.y), acc[2]);
        acc[3] = fmaf(a1, bf_hi(d1.y), acc[3]);
        acc[4] = fmaf(a1, bf_lo(d1.z), acc[4]);
        acc[5] = fmaf(a1, bf_hi(d1.z), acc[5]);
        acc[6] = fmaf(a1, bf_lo(d1.w), acc[6]);
        acc[7] = fmaf(a1, bf_hi(d1.w), acc[7]);
    }
    if (e < e1) {                      // remainder exactly EPW
        int2 p0 = rec[e + g];
        float a0 = __int_as_float(p0.y);
        uint4 d0 = *(const uint4*)(ego2_bf + (unsigned)(p0.x * 32) + q * 8);
        acc[0] = fmaf(a0, bf_lo(d0.x), acc[0]);
        acc[1] = fmaf(a0, bf_hi(d0.x), acc[1]);
        acc[2] = fmaf(a0, bf_lo(d0.y), acc[2]);
        acc[3] = fmaf(a0, bf_hi(d0.y), acc[3]);
        acc[4] = fmaf(a0, bf_lo(d0.z), acc[4]);
        acc[5] = fmaf(a0, bf_hi(d0.z), acc[5]);
        acc[6] = fmaf(a0, bf_lo(d0.w), acc[6]);
        acc[7] = fmaf(a0, bf_hi(d0.w), acc[7]);
    }

    #pragma unroll
    for (int off = LPR; off < 64; off <<= 1)
        #pragma unroll
        for (int j = 0; j < 8; ++j) acc[j] += __shfl_xor(acc[j], off, 64);
    // every lane now holds side2 chunk q: elements [q*8 .. q*8+7]

    // U = ego2 + side2, V = ego2 * side2 for this lane's chunk
    uint4 dd = *(const uint4*)(ego2_bf + (size_t)node * 32 + q * 8);
    float Uc[8], Vc[8];
    {
        float ev[8] = { bf_lo(dd.x), bf_hi(dd.x), bf_lo(dd.y), bf_hi(dd.y),
                        bf_lo(dd.z), bf_hi(dd.z), bf_lo(dd.w), bf_hi(dd.w) };
        #pragma unroll
        for (int j = 0; j < 8; ++j) { Uc[j] = ev[j] + acc[j]; Vc[j] = ev[j] * acc[j]; }
    }

    // transform 32->16 (transform_k's exact k-ascending chain), lanes 0..15
    if (lane < 16) {
        float accg = 0.f, accb = 0.f;
        #pragma unroll
        for (int k = 0; k < 32; ++k) {
            float u = __shfl(Uc[k & 7], k >> 3, 64);   // src lanes 0..3 (active)
            float v = __shfl(Vc[k & 7], k >> 3, 64);
            accg = fmaf(u, sWgc[k * 16 + lane], accg);
            accb = fmaf(v, sWbi[k * 16 + lane], accb);
        }
        float gg = accg + bgc[lane];
        float b2 = accb + bbi[lane];
        gg = gg > 0.f ? gg : SLOPE * gg;
        b2 = b2 > 0.f ? b2 : SLOPE * b2;
        float x3 = gg + b2;
        float ss3 = x3 * x3;
        #pragma unroll
        for (int off = 8; off > 0; off >>= 1) ss3 += __shfl_xor(ss3, off, 64);
        o[160 + lane] = x3 / fmaxf(sqrtf(ss3), EPSF);
    }
}

// ---------------------------------------------------------------------------
extern "C" void kernel_launch(void* const* d_in, const int* in_sizes, int n_in,
                              void* d_out, int out_size, void* d_ws, size_t ws_size,
                              hipStream_t stream) {
    const int*   users    = (const int*)d_in[0];
    const int*   pos      = (const int*)d_in[1];
    const int*   neg      = (const int*)d_in[2];
    const int*   all_h    = (const int*)d_in[3];
    const int*   all_t    = (const int*)d_in[4];
    const float* A        = (const float*)d_in[5];
    const float* user_emb = (const float*)d_in[6];
    const float* ent_emb  = (const float*)d_in[7];
    const float* Wgc0 = (const float*)d_in[8];
    const float* bgc0 = (const float*)d_in[9];
    const float* Wbi0 = (const float*)d_in[10];
    const float* bbi0 = (const float*)d_in[11];
    const float* Wgc1 = (const float*)d_in[12];
    const float* bgc1 = (const float*)d_in[13];
    const float* Wbi1 = (const float*)d_in[14];
    const float* bbi1 = (const float*)d_in[15];
    const float* Wgc2 = (const float*)d_in[16];
    const float* bgc2 = (const float*)d_in[17];
    const float* Wbi2 = (const float*)d_in[18];
    const float* bbi2 = (const float*)d_in[19];

    // ---- workspace (256B-aligned).
    // rec_src (24MB) aliases side (37.5MB): rec_src dead after local_sort,
    // side first written by side_k afterwards.
    char* p = (char*)d_ws;
    int*   prefix  = (int*)p;            p += ((size_t)NPB * PFW * 4 + 255) & ~255ull;
    float* side    = (float*)p;
    int2*  rec_src = (int2*)p;           p += ((size_t)N_NODES * 64 * 4 + 255) & ~255ull;
    int2*  rec     = (int2*)p;           p += ((size_t)NBUK * STR * 8 + 255) & ~255ull;
    int2*  range   = (int2*)p;           p += ((size_t)N_NODES * 8 + 255) & ~255ull;
    unsigned short* ego0_bf = (unsigned short*)p; p += ((size_t)N_NODES * 64 * 2 + 255) & ~255ull;
    unsigned short* ego1_bf = (unsigned short*)p; p += ((size_t)N_NODES * 64 * 2 + 255) & ~255ull;
    unsigned short* ego2_bf = (unsigned short*)p; p += ((size_t)N_NODES * 32 * 2 + 255) & ~255ull;
    float* out     = (float*)d_out;

    const int nodeBlocks = N_NODES / 4;

    // ---- prep: merged {block-local partition + bf16 cast} + bucket assembly
    prep_k<<<NPB + CASTB, PBLK, 0, stream>>>(all_h, all_t, A, prefix, rec_src,
                                             user_emb, ent_emb, ego0_bf);
    local_sort_k<<<NBUK, 256, 0, stream>>>(prefix, rec_src, rec, range);

    // ---- layer 0: 64 -> 64 ----
    side_k<64><<<nodeBlocks, 256, 0, stream>>>(range, rec, ego0_bf, side);
    transform_k<64, 64, 64, true><<<(N_NODES + 63) / 64, 256, 0, stream>>>(
        nullptr, user_emb, ent_emb, side, Wgc0, bgc0, Wbi0, bbi0, ego1_bf);

    // ---- layer 1: 64 -> 32 ----
    side_k<64><<<nodeBlocks, 256, 0, stream>>>(range, rec, ego1_bf, side);
    transform_k<64, 32, 64, false><<<(N_NODES + 63) / 64, 256, 0, stream>>>(
        ego1_bf, nullptr, nullptr, side, Wgc1, bgc1, Wbi1, bbi1, ego2_bf);

    // ---- layer 2 (lazy, sampled rows only) + gather + normalization ----
    final_k<<<3 * BATCH / 4, 256, 0, stream>>>(
        users, pos, neg, user_emb, ent_emb, ego1_bf, ego2_bf,
        range, rec, Wgc2, bgc2, Wbi2, bbi2, out);
}